// Round 18
// baseline (303.234 us; speedup 1.0000x reference)
//
#include <hip/hip_runtime.h>
#include <hip/hip_bf16.h>
#include <math.h>

#define Bb 2
#define Tt 512
#define HIDD 1024
#define Hh 16
#define Dd 64
#define Pp 1024
#define Kc 4
#define Ee 8
#define Ii 768
#define ISs 768
#define Ntok (Bb*Tt)   // 1024
#define NASSIGN (2*Ntok)  // 2048
#define NTOT (NASSIGN + Ntok)  // 3072 incl shared
#define SCH 8
#define SNCH (Tt/SCH)  // 64
#define NQKV 3200      // 3072 qkv cols + 128 fg cols

typedef __attribute__((ext_vector_type(8))) short bf16x8;
typedef __attribute__((ext_vector_type(4))) float floatx4;

__device__ __forceinline__ float sigmoidf_(float x){ return 1.f/(1.f+expf(-x)); }
__device__ __forceinline__ float siluf_(float x){ return x/(1.f+expf(-x)); }
__device__ __forceinline__ float bf2f(__hip_bfloat16 b){ return __bfloat162float(b); }

__device__ __forceinline__ void async16(void* lds, const void* g) {
  __builtin_amdgcn_global_load_lds(
      (const __attribute__((address_space(1))) void*)g,
      (__attribute__((address_space(3))) void*)lds, 16, 0, 0);
}

template<int CTRL>
__device__ __forceinline__ float dpp_add(float x){
  int y = __builtin_amdgcn_update_dpp(0, __float_as_int(x), CTRL, 0xF, 0xF, true);
  return x + __int_as_float(y);
}

__device__ __forceinline__ void ds_read128(floatx4& d, const float* p){
  asm volatile("ds_read_b128 %0, %1"
    : "=v"(d)
    : "v"((const __attribute__((address_space(3))) float*)p));
}
__device__ __forceinline__ void ds_read32f(float& d, const float* p){
  asm volatile("ds_read_b32 %0, %1"
    : "=v"(d)
    : "v"((const __attribute__((address_space(3))) float*)p));
}

// ========== RMS norm + beta fused ==========
__global__ void rms_beta_split_kernel(const float* __restrict__ x, const float* __restrict__ w,
                                      const float* __restrict__ bp,
                                      __hip_bfloat16* __restrict__ hi, __hip_bfloat16* __restrict__ lo,
                                      float* __restrict__ betab, float eps) {
  int row = blockIdx.x;
  const float* xr = x + (size_t)row*HIDD;
  float s = 0.f;
  for (int i = threadIdx.x; i < HIDD; i += 256){ float v = xr[i]; s += v*v; }
  #pragma unroll
  for (int off=32; off; off>>=1) s += __shfl_down(s, off, 64);
  __shared__ float red[4];
  if ((threadIdx.x & 63)==0) red[threadIdx.x>>6] = s;
  __syncthreads();
  float tot = red[0]+red[1]+red[2]+red[3];
  float sc = rsqrtf(tot/(float)HIDD + eps);
  float bacc[16] = {};
  for (int i = threadIdx.x; i < HIDD; i += 256) {
    float v = xr[i]*sc*w[i];
    __hip_bfloat16 h = __float2bfloat16(v);
    hi[(size_t)row*HIDD+i] = h;
    lo[(size_t)row*HIDD+i] = __float2bfloat16(v - bf2f(h));
    #pragma unroll
    for (int n=0;n<16;n++) bacc[n] += v * bp[i*16+n];
  }
  #pragma unroll
  for (int n=0;n<16;n++){
    #pragma unroll
    for (int off=32; off; off>>=1) bacc[n] += __shfl_down(bacc[n], off, 64);
  }
  __shared__ float redb[4][16];
  if ((threadIdx.x & 63)==0){
    #pragma unroll
    for (int n=0;n<16;n++) redb[threadIdx.x>>6][n] = bacc[n];
  }
  __syncthreads();
  if (threadIdx.x < 16)
    betab[(size_t)row*16 + threadIdx.x] =
      sigmoidf_(redb[0][threadIdx.x]+redb[1][threadIdx.x]+redb[2][threadIdx.x]+redb[3][threadIdx.x]);
}

// ===== batched split transpose: z 0..3 = wq/wk/wv/wo (1024x1024); z 4/5 = fa/ga (1024x64)
//       fa/ga land in rows 3072.. of the qkv weight buffers =====
__global__ void trans_split6_kernel(const float* __restrict__ wq, const float* __restrict__ wk,
                                    const float* __restrict__ wv, const float* __restrict__ wo,
                                    const float* __restrict__ fa, const float* __restrict__ ga,
                                    __hip_bfloat16* __restrict__ qkv_hi, __hip_bfloat16* __restrict__ qkv_lo,
                                    __hip_bfloat16* __restrict__ wo_hi, __hip_bfloat16* __restrict__ wo_lo) {
  int z = blockIdx.z;
  int n0 = blockIdx.x*32, k0 = blockIdx.y*32;
  const float* src; __hip_bfloat16* hi; __hip_bfloat16* lo; int N;
  if (z < 4) {
    src = (z==0)?wq:(z==1)?wk:(z==2)?wv:wo;
    hi = (z<3) ? qkv_hi + (size_t)z*Pp*HIDD : wo_hi;
    lo = (z<3) ? qkv_lo + (size_t)z*Pp*HIDD : wo_lo;
    N = 1024;
  } else {
    if (n0 >= 64) return;
    src = (z==4) ? fa : ga;
    lo = qkv_lo + (size_t)(3072 + (z-4)*64)*HIDD;
    hi = qkv_hi + (size_t)(3072 + (z-4)*64)*HIDD;
    N = 64;
  }
  __shared__ float tile[32][33];
  int tx = threadIdx.x & 31, ty0 = threadIdx.x >> 5;
  #pragma unroll
  for (int j=0;j<4;j++){ int ty = ty0 + j*8; tile[ty][tx] = src[(size_t)(k0+ty)*N + n0+tx]; }
  __syncthreads();
  #pragma unroll
  for (int j=0;j<4;j++){
    int ty = ty0 + j*8;
    float v = tile[tx][ty];
    __hip_bfloat16 h = __float2bfloat16(v);
    hi[(size_t)(n0+ty)*HIDD + k0+tx] = h;
    lo[(size_t)(n0+ty)*HIDD + k0+tx] = __float2bfloat16(v - bf2f(h));
  }
}

// ===== fbgb: fb rows 0..1023 (k 0..63, zeros 64..127), gb rows 1024..2047 (k 64..127) =====
__global__ void trans_fbgb_kernel(const float* __restrict__ fb, const float* __restrict__ gb,
                                  __hip_bfloat16* __restrict__ dst) {
  int z = blockIdx.z;
  const float* src = z ? gb : fb;
  __shared__ float tile[32][33];
  int n0 = blockIdx.x*32, k0 = blockIdx.y*32;
  int tx = threadIdx.x & 31, ty0 = threadIdx.x >> 5;
  #pragma unroll
  for (int j=0;j<4;j++){ int ty = ty0 + j*8; tile[ty][tx] = src[(size_t)(k0+ty)*Pp + n0+tx]; }
  __syncthreads();
  #pragma unroll
  for (int j=0;j<4;j++){
    int ty = ty0 + j*8;
    size_t row = (size_t)(z*1024 + n0+ty);
    dst[row*128 + (z?64:0) + k0+tx] = __float2bfloat16(tile[tx][ty]);
    dst[row*128 + (z?0:64) + k0+tx] = __float2bfloat16(0.f);
  }
}

// ====== merged expert weight transpose: z 0..17 up (interleaved), z 18..26 down ======
__global__ void trans_expert_kernel(const float* __restrict__ wg_e, const float* __restrict__ wu_e,
                                    const float* __restrict__ wg_s, const float* __restrict__ wu_s,
                                    const float* __restrict__ wd_e, const float* __restrict__ wd_s,
                                    __hip_bfloat16* __restrict__ up_dst, __hip_bfloat16* __restrict__ dn_dst) {
  int z = blockIdx.z;
  __shared__ float tile[32][33];
  int n0 = blockIdx.x*32, k0 = blockIdx.y*32;
  int tx = threadIdx.x & 31, ty0 = threadIdx.x >> 5;
  if (z < 18) {
    if (n0 >= Ii) return;
    int e = z >> 1, phase = z & 1;
    const float* src = (e < 8) ? ((phase ? wu_e : wg_e) + (size_t)e*HIDD*Ii)
                               : (phase ? wu_s : wg_s);
    __hip_bfloat16* dst = up_dst + (size_t)e*(2*Ii*HIDD);
    #pragma unroll
    for (int j=0;j<4;j++){ int ty = ty0 + j*8; tile[ty][tx] = src[(size_t)(k0+ty)*Ii + n0+tx]; }
    __syncthreads();
    #pragma unroll
    for (int j=0;j<4;j++){
      int ty = ty0 + j*8;
      dst[(size_t)(2*(n0+ty)+phase)*HIDD + k0+tx] = __float2bfloat16(tile[tx][ty]);
    }
  } else {
    if (k0 >= Ii) return;
    int e = z - 18;
    const float* src = (e < 8) ? wd_e + (size_t)e*Ii*HIDD : wd_s;
    __hip_bfloat16* dst = dn_dst + (size_t)e*HIDD*Ii;
    #pragma unroll
    for (int j=0;j<4;j++){ int ty = ty0 + j*8; tile[ty][tx] = src[(size_t)(k0+ty)*HIDD + n0+tx]; }
    __syncthreads();
    #pragma unroll
    for (int j=0;j<4;j++){ int ty = ty0 + j*8; dst[(size_t)(n0+ty)*Ii + k0+tx] = __float2bfloat16(tile[tx][ty]); }
  }
}

// ================= MFMA GEMM core: BM=64, BN = BND (64 or 128), 4 waves =================
__device__ __forceinline__ int lds_off(int row, int slot){
  return row*128 + (((slot ^ row)&7)<<4);
}

// MODE 1: bf16 out. 4: expert scatter (routed [tok][3][N]). 6: expert GLU with INDIRECT
// A-gather via ctok. 8: fb|gb fused (cols<1024 g-transform -> C; else f32 -> ctok).
template<int MODE, int ACC, int BND>
__global__ __launch_bounds__(256)
void gemm_k(const __hip_bfloat16* __restrict__ A, const __hip_bfloat16* __restrict__ BT,
            void* __restrict__ C, int M, int N, int K, int lda, const float* __restrict__ resid,
            const int* __restrict__ counts, const int* __restrict__ prefix,
            const int* __restrict__ ctok, const int* __restrict__ cslot,
            const float* __restrict__ cwt) {
  constexpr int NF = BND/32;
  int Me = M;
  int moff = 0;
  if (MODE == 4 || MODE == 6) {
    int e = blockIdx.z;
    Me = counts[e]; moff = prefix[e];
    if (MODE == 4) A += (size_t)moff * lda;
    BT += (size_t)e * (size_t)N * K;
  }
  int row0 = blockIdx.y * 64;
  if (row0 >= Me) return;
  int col0 = blockIdx.x * BND;

  __shared__ __attribute__((aligned(16))) short As[64*64];
  __shared__ __attribute__((aligned(16))) short Bs[BND*64];
  __shared__ int sidx[64];
  const int lane = threadIdx.x & 63;
  const int w    = threadIdx.x >> 6;
  const int wr = w >> 1, wc = w & 1;
  const int srow = lane >> 3;
  const int sch  = (lane & 7) ^ (srow & 7);
  const int q = lane >> 4, r16 = lane & 15;

  if (MODE == 6) {
    if (threadIdx.x < 64) {
      int rr = row0 + threadIdx.x;
      sidx[threadIdx.x] = (rr < Me) ? ctok[moff + rr] : 0;
    }
    __syncthreads();
  }

  const __hip_bfloat16* Ag = A  + (size_t)row0 * lda;
  const __hip_bfloat16* Bg = BT + (size_t)col0 * K;

  floatx4 acc[2][NF] = {};

  for (int k0 = 0; k0 < K; k0 += 64) {
    #pragma unroll
    for (int ii = 0; ii < 2; ++ii) {
      const int inst = w + ii*4;
      const int r = inst*8 + srow;
      if (MODE == 6)
        async16((char*)As + inst*1024, A + (size_t)sidx[r]*lda + (size_t)(k0 + sch*8));
      else
        async16((char*)As + inst*1024, Ag + (size_t)r*lda + (size_t)(k0 + sch*8));
    }
    #pragma unroll
    for (int ii = 0; ii < BND/32; ++ii) {
      const int inst = w + ii*4;
      const int r = inst*8 + srow;
      async16((char*)Bs + inst*1024, Bg + (size_t)r*K + (size_t)(k0 + sch*8));
    }
    __syncthreads();
    #pragma unroll
    for (int kk = 0; kk < 2; ++kk) {
      int slot = kk*4 + q;
      bf16x8 a0 = *(const bf16x8*)((const char*)As + lds_off(wr*32 +      r16, slot));
      bf16x8 a1 = *(const bf16x8*)((const char*)As + lds_off(wr*32 + 16 + r16, slot));
      bf16x8 b[NF];
      #pragma unroll
      for (int ni=0; ni<NF; ++ni)
        b[ni] = *(const bf16x8*)((const char*)Bs + lds_off(wc*(BND/2) + ni*16 + r16, slot));
      #pragma unroll
      for (int ni=0; ni<NF; ++ni){
        acc[0][ni] = __builtin_amdgcn_mfma_f32_16x16x32_bf16(a0, b[ni], acc[0][ni], 0, 0, 0);
        acc[1][ni] = __builtin_amdgcn_mfma_f32_16x16x32_bf16(a1, b[ni], acc[1][ni], 0, 0, 0);
      }
    }
    __syncthreads();
  }

  #pragma unroll
  for (int mi = 0; mi < 2; ++mi) {
    #pragma unroll
    for (int r = 0; r < 4; ++r) {
      int grow = row0 + wr*32 + mi*16 + q*4 + r;
      if (grow >= Me) continue;
      #pragma unroll
      for (int ni = 0; ni < NF; ++ni) {
        int gcol = col0 + wc*(BND/2) + ni*16 + r16;
        float v = acc[mi][ni][r];
        if (MODE == 1) {
          ((__hip_bfloat16*)C)[(size_t)grow*N + gcol] = __float2bfloat16(v);
        } else if (MODE == 4) {
          int rc = moff + grow;
          int tok = ctok[rc], sl = cslot[rc];
          ((__hip_bfloat16*)C)[((size_t)tok*3 + sl)*N + gcol] = __float2bfloat16(cwt[rc]*v);
        } else if (MODE == 6) {
          float pv = __shfl_xor(v, 1, 64);
          if ((lane & 1) == 0) {
            float rglu = siluf_(v) * pv;
            ((__hip_bfloat16*)C)[(size_t)(moff+grow)*(N/2) + (gcol>>1)] = __float2bfloat16(rglu);
          }
        } else if (MODE == 8) {
          if (gcol < 1024) {
            int hh2 = gcol >> 6, d2 = gcol & 63;
            float t2 = v + cwt[hh2*64 + d2];
            float sp = (t2 > 20.f) ? t2 : log1pf(expf(t2));
            ((float*)C)[(size_t)grow*1024 + gcol] = expf(-expf(resid[hh2]) * sp);
          } else {
            ((float*)(size_t)ctok)[(size_t)grow*1024 + (gcol-1024)] = v;
          }
        }
      }
    }
  }
}

// 3-phase split-bf16 GEMM, merged staging.
// MODE 0: f32 out. 2: f32 + resid. 3: QKV+fg fused (col<3072 -> f32 qkvlin stride 3072;
//   col>=3072 -> bf16 atmp12 (via resid ptr) stride 128).
template<int MODE, int BND>
__global__ __launch_bounds__(256)
void gemm3_k(const __hip_bfloat16* __restrict__ Ahi, const __hip_bfloat16* __restrict__ Alo,
             const __hip_bfloat16* __restrict__ Bhi, const __hip_bfloat16* __restrict__ Blo,
             float* __restrict__ C, int M, int N, int K, const float* __restrict__ resid) {
  constexpr int NF = BND/32;
  int row0 = blockIdx.y * 64;
  int col0 = blockIdx.x * BND;

  __shared__ __attribute__((aligned(16))) short As[64*64];
  __shared__ __attribute__((aligned(16))) short Bs[2][BND*64];
  const int lane = threadIdx.x & 63;
  const int w    = threadIdx.x >> 6;
  const int wr = w >> 1, wc = w & 1;
  const int srow = lane >> 3;
  const int sch  = (lane & 7) ^ (srow & 7);
  const int q = lane >> 4, r16 = lane & 15;

  const __hip_bfloat16* Ag0 = Ahi + (size_t)row0 * K;
  const __hip_bfloat16* Ag1 = Alo + (size_t)row0 * K;
  const __hip_bfloat16* Bg0 = Bhi + (size_t)col0 * K;
  const __hip_bfloat16* Bg1 = Blo + (size_t)col0 * K;

  floatx4 acc[2][NF] = {};

  // phase A: Ahi * (Bhi + Blo)
  for (int k0 = 0; k0 < K; k0 += 64) {
    #pragma unroll
    for (int ii = 0; ii < 2; ++ii) {
      const int inst = w + ii*4;
      const int r = inst*8 + srow;
      async16((char*)As + inst*1024, Ag0 + (size_t)r*K + (size_t)(k0 + sch*8));
    }
    #pragma unroll
    for (int ii = 0; ii < BND/32; ++ii) {
      const int inst = w + ii*4;
      const int r = inst*8 + srow;
      async16((char*)Bs[0] + inst*1024, Bg0 + (size_t)r*K + (size_t)(k0 + sch*8));
      async16((char*)Bs[1] + inst*1024, Bg1 + (size_t)r*K + (size_t)(k0 + sch*8));
    }
    __syncthreads();
    #pragma unroll
    for (int kk = 0; kk < 2; ++kk) {
      int slot = kk*4 + q;
      bf16x8 a0 = *(const bf16x8*)((const char*)As + lds_off(wr*32 +      r16, slot));
      bf16x8 a1 = *(const bf16x8*)((const char*)As + lds_off(wr*32 + 16 + r16, slot));
      #pragma unroll
      for (int pb = 0; pb < 2; ++pb) {
        bf16x8 b[NF];
        #pragma unroll
        for (int ni=0; ni<NF; ++ni)
          b[ni] = *(const bf16x8*)((const char*)Bs[pb] + lds_off(wc*(BND/2) + ni*16 + r16, slot));
        #pragma unroll
        for (int ni=0; ni<NF; ++ni){
          acc[0][ni] = __builtin_amdgcn_mfma_f32_16x16x32_bf16(a0, b[ni], acc[0][ni], 0, 0, 0);
          acc[1][ni] = __builtin_amdgcn_mfma_f32_16x16x32_bf16(a1, b[ni], acc[1][ni], 0, 0, 0);
        }
      }
    }
    __syncthreads();
  }
  // phase B: Alo * Bhi
  for (int k0 = 0; k0 < K; k0 += 64) {
    #pragma unroll
    for (int ii = 0; ii < 2; ++ii) {
      const int inst = w + ii*4;
      const int r = inst*8 + srow;
      async16((char*)As + inst*1024, Ag1 + (size_t)r*K + (size_t)(k0 + sch*8));
    }
    #pragma unroll
    for (int ii = 0; ii < BND/32; ++ii) {
      const int inst = w + ii*4;
      const int r = inst*8 + srow;
      async16((char*)Bs[0] + inst*1024, Bg0 + (size_t)r*K + (size_t)(k0 + sch*8));
    }
    __syncthreads();
    #pragma unroll
    for (int kk = 0; kk < 2; ++kk) {
      int slot = kk*4 + q;
      bf16x8 a0 = *(const bf16x8*)((const char*)As + lds_off(wr*32 +      r16, slot));
      bf16x8 a1 = *(const bf16x8*)((const char*)As + lds_off(wr*32 + 16 + r16, slot));
      bf16x8 b[NF];
      #pragma unroll
      for (int ni=0; ni<NF; ++ni)
        b[ni] = *(const bf16x8*)((const char*)Bs[0] + lds_off(wc*(BND/2) + ni*16 + r16, slot));
      #pragma unroll
      for (int ni=0; ni<NF; ++ni){
        acc[0][ni] = __builtin_amdgcn_mfma_f32_16x16x32_bf16(a0, b[ni], acc[0][ni], 0, 0, 0);
        acc[1][ni] = __builtin_amdgcn_mfma_f32_16x16x32_bf16(a1, b[ni], acc[1][ni], 0, 0, 0);
      }
    }
    __syncthreads();
  }

  #pragma unroll
  for (int mi = 0; mi < 2; ++mi) {
    #pragma unroll
    for (int r = 0; r < 4; ++r) {
      int grow = row0 + wr*32 + mi*16 + q*4 + r;
      #pragma unroll
      for (int ni = 0; ni < NF; ++ni) {
        int gcol = col0 + wc*(BND/2) + ni*16 + r16;
        float v = acc[mi][ni][r];
        if (MODE == 3) {
          if (gcol < 3072)
            C[(size_t)grow*3072 + gcol] = v;
          else
            ((__hip_bfloat16*)(size_t)resid)[(size_t)grow*128 + (gcol-3072)] = __float2bfloat16(v);
        } else {
          if (MODE == 2) v += resid[(size_t)grow*N + gcol];
          C[(size_t)grow*N + gcol] = v;
        }
      }
    }
  }
}

// ================= fused causal dwconv(K=4) + SiLU + (L2 norm for q/k) =================
__global__ void conv_norm_kernel(const float* __restrict__ in,
                                 const float* __restrict__ cq, const float* __restrict__ ck,
                                 const float* __restrict__ cv,
                                 float* __restrict__ qc, float* __restrict__ kc,
                                 float* __restrict__ vc) {
  int tok = blockIdx.x;
  int mode = blockIdx.y;
  const float* w = (mode==0) ? cq : (mode==1) ? ck : cv;
  float* outp    = (mode==0) ? qc : (mode==1) ? kc : vc;
  int colOff = mode << 10;
  int t = threadIdx.x;
  int c0 = t*4;
  int tloc = tok & (Tt-1);

  float wv[4][4];
  #pragma unroll
  for (int i=0;i<4;i++){
    float4 w4 = ((const float4*)w)[c0+i];
    wv[i][0]=w4.x; wv[i][1]=w4.y; wv[i][2]=w4.z; wv[i][3]=w4.w;
  }
  float acc[4] = {0.f,0.f,0.f,0.f};
  #pragma unroll
  for (int j=0;j<Kc;j++){
    int tt = tloc - (Kc-1) + j;
    if (tt >= 0){
      float4 xv = *(const float4*)&in[(size_t)(tok-(Kc-1)+j)*3072 + colOff + c0];
      acc[0] += wv[0][j]*xv.x;
      acc[1] += wv[1][j]*xv.y;
      acc[2] += wv[2][j]*xv.z;
      acc[3] += wv[3][j]*xv.w;
    }
  }
  float val[4];
  #pragma unroll
  for (int i=0;i<4;i++) val[i] = siluf_(acc[i]);
  float scale = 1.f;
  if (mode < 2) {
    float ss = val[0]*val[0]+val[1]*val[1]+val[2]*val[2]+val[3]*val[3];
    ss += __shfl_xor(ss, 1, 64);
    ss += __shfl_xor(ss, 2, 64);
    ss += __shfl_xor(ss, 4, 64);
    ss += __shfl_xor(ss, 8, 64);
    scale = rsqrtf(ss/(float)Dd + 1e-6f) * ((mode==0) ? (1.f/64.f) : 0.125f);
  }
  float4 o4 = make_float4(val[0]*scale, val[1]*scale, val[2]*scale, val[3]*scale);
  *(float4*)&outp[(size_t)tok*Pp + c0] = o4;
}

// ===== fused: hn = rms(h)*w2 (bf16), router logits (fp32) =====
__global__ void moe_rms_scores_kernel(const float* __restrict__ h, const float* __restrict__ w2,
                                      const float* __restrict__ gw,
                                      __hip_bfloat16* __restrict__ hn, float* __restrict__ scores) {
  int row = blockIdx.x;
  const float* hr = h + (size_t)row*HIDD;
  float s = 0.f;
  for (int i = threadIdx.x; i < HIDD; i += 256){ float v = hr[i]; s += v*v; }
  #pragma unroll
  for (int off=32; off; off>>=1) s += __shfl_down(s, off, 64);
  __shared__ float red[4];
  if ((threadIdx.x & 63)==0) red[threadIdx.x>>6] = s;
  __syncthreads();
  float sc = rsqrtf((red[0]+red[1]+red[2]+red[3])/(float)HIDD + 1e-5f);
  float acc[Ee] = {};
  for (int i = threadIdx.x; i < HIDD; i += 256){
    float xv = hr[i]*sc*w2[i];
    hn[(size_t)row*HIDD + i] = __float2bfloat16(xv);
    #pragma unroll
    for (int e=0;e<Ee;e++) acc[e] += xv*gw[i*Ee+e];
  }
  #pragma unroll
  for (int e=0;e<Ee;e++){
    #pragma unroll
    for (int off=32; off; off>>=1) acc[e] += __shfl_down(acc[e], off, 64);
  }
  __shared__ float red2[4][Ee];
  if ((threadIdx.x & 63)==0){
    #pragma unroll
    for (int e=0;e<Ee;e++) red2[threadIdx.x>>6][e] = acc[e];
  }
  __syncthreads();
  if (threadIdx.x < Ee)
    scores[(size_t)row*Ee + threadIdx.x] =
      red2[0][threadIdx.x]+red2[1][threadIdx.x]+red2[2][threadIdx.x]+red2[3][threadIdx.x];
}

// ================= delta-rule scan v6 (79 us proven) =================
#define REGLOAD(bufi, tbase, K,G,Q,VV,BT) do { \
  const int _b = (bufi); const int _t0 = (tbase); \
  _Pragma("unroll") \
  for (int _i=0;_i<SCH;_i++){ \
    ds_read128(K[_i], &sk[_b][_i][kq*4]); \
    ds_read128(G[_i], &sg[_b][_i][kq*4]); \
    ds_read128(Q[_i], &sq[_b][_i][kq*4]); \
    ds_read32f(VV[_i], &sbv[_t0+_i][vi]); \
    ds_read32f(BT[_i], &sb[_t0+_i]); \
  } \
} while(0)

#define SSTEP(K,G,Q,VV,BT,_i,_t) do { \
  floatx4 k4=K[_i], g4=G[_i], q4=Q[_i]; \
  float vvv=VV[_i], bt=BT[_i]; \
  S0*=g4.x; S1*=g4.y; S2*=g4.z; S3*=g4.w; \
  float pred = S0*k4.x + S1*k4.y + S2*k4.z + S3*k4.w; \
  pred = dpp_add<0xB1>(pred); pred = dpp_add<0x4E>(pred); \
  pred = dpp_add<0x141>(pred); pred = dpp_add<0x140>(pred); \
  float upd = (vvv - pred) * bt; \
  S0 += k4.x*upd; S1 += k4.y*upd; S2 += k4.z*upd; S3 += k4.w*upd; \
  float acc = S0*q4.x + S1*q4.y + S2*q4.z + S3*q4.w; \
  acc = dpp_add<0xB1>(acc); acc = dpp_add<0x4E>(acc); \
  acc = dpp_add<0x141>(acc); acc = dpp_add<0x140>(acc); \
  if (kq == 0) so[_t][vi] = acc; \
} while(0)

#define SITER(c, KC,GC,QC,VC,BC, KN,GN,QN,VN,BN) do { \
  if ((c)+1 < SNCH) { \
    if ((c)+2 < SNCH) asm volatile("s_waitcnt vmcnt(6)" ::: "memory"); \
    else              asm volatile("s_waitcnt vmcnt(0)" ::: "memory"); \
    REGLOAD(((c)+1)%3, ((c)+1)*SCH, KN,GN,QN,VN,BN); \
    if ((c)+3 < SNCH) stage(((c)+3)*SCH, ((c)+3)%3); \
  } \
  _Pragma("unroll") \
  for (int _s=0;_s<SCH;_s++) SSTEP(KC,GC,QC,VC,BC,_s,(c)*SCH+_s); \
  asm volatile("s_waitcnt lgkmcnt(0)" ::: "memory"); \
  __builtin_amdgcn_sched_barrier(0); \
} while(0)

__global__ __launch_bounds__(64)
void scan_kernel(const float* __restrict__ q, const float* __restrict__ k,
                 const float* __restrict__ v, const float* __restrict__ g,
                 const float* __restrict__ beta, float* __restrict__ o) {
  const int vb = blockIdx.x & 15;
  const int hh = (blockIdx.x >> 4) & 15;
  const int b  = blockIdx.x >> 8;
  const int lane = threadIdx.x;
  const int kq = lane & 15;
  const int vi = lane >> 4;
  const int v0 = vb*4;
  const int rb = b*Tt;

  __shared__ __attribute__((aligned(16))) float sq[3][SCH][64];
  __shared__ __attribute__((aligned(16))) float sk[3][SCH][64];
  __shared__ __attribute__((aligned(16))) float sg[3][SCH][64];
  __shared__ __attribute__((aligned(16))) float sbv[Tt][4];
  __shared__ float sb[Tt];
  __shared__ __attribute__((aligned(16))) float so[Tt][4];

  #pragma unroll
  for (int i=0;i<Tt/64;i++)
    sb[i*64+lane] = beta[(size_t)(rb + i*64 + lane)*Hh + hh];
  asm volatile("s_waitcnt vmcnt(0)" ::: "memory");

  #pragma unroll
  for (int i=0;i<Tt/64;i++)
    async16(&sbv[i*64][0], v + (size_t)(rb + i*64 + lane)*Pp + hh*64 + v0);

  auto stage = [&](int t0, int buf) {
    const int srow = lane >> 4, sch4 = (lane & 15)*4;
    #pragma unroll
    for (int ii=0; ii<2; ++ii) {
      size_t gbase = (size_t)(rb + t0 + ii*4 + srow)*Pp + hh*64;
      async16(&sq[buf][ii*4][0], q + gbase + sch4);
      async16(&sk[buf][ii*4][0], k + gbase + sch4);
      async16(&sg[buf][ii*4][0], g + gbase + sch4);
    }
  };

  floatx4 Ka[SCH],Ga[SCH],Qa[SCH], Kb[SCH],Gb[SCH],Qb[SCH];
  float Va[SCH],Bta[SCH], Vb2[SCH],Btb[SCH];
  float S0=0.f,S1=0.f,S2=0.f,S3=0.f;

  stage(0, 0);
  stage(SCH, 1);
  asm volatile("s_waitcnt vmcnt(6)" ::: "memory");
  REGLOAD(0, 0, Ka,Ga,Qa,Va,Bta);
  stage(2*SCH, 2);
  asm volatile("s_waitcnt lgkmcnt(0)" ::: "memory");
  __builtin_amdgcn_sched_barrier(0);

  for (int cp = 0; cp < SNCH; cp += 2) {
    SITER(cp,   Ka,Ga,Qa,Va,Bta, Kb,Gb,Qb,Vb2,Btb);
    SITER(cp+1, Kb,Gb,Qb,Vb2,Btb, Ka,Ga,Qa,Va,Bta);
  }

  #pragma unroll
  for (int i=0;i<Tt/64;i++){
    int t = i*64 + lane;
    *(float4*)&o[(size_t)(rb+t)*Pp + hh*64 + v0] = *(const float4*)&so[t][0];
  }
}

// ================= o = rms(o)*w*sigmoid(gate) -> split hi/lo bf16 =================
__global__ void onorm_gate_split_kernel(const float* __restrict__ o, const float* __restrict__ w,
                                        const float* __restrict__ gate,
                                        __hip_bfloat16* __restrict__ hi, __hip_bfloat16* __restrict__ lo) {
  int row = blockIdx.x*4 + (threadIdx.x>>6);
  int lane = threadIdx.x & 63;
  size_t idx = (size_t)row*Dd + lane;
  float v = o[idx];
  float s = v*v;
  #pragma unroll
  for (int off=32; off; off>>=1) s += __shfl_xor(s, off, 64);
  float r = v * rsqrtf(s/(float)Dd + 1e-5f) * w[lane] * sigmoidf_(gate[idx]);
  __hip_bfloat16 h = __float2bfloat16(r);
  hi[idx] = h;
  lo[idx] = __float2bfloat16(r - bf2f(h));
}

// ===== fused router + compact + prefix + shared tail (single block, 1024 threads) =====
__global__ void router_compact_kernel(const float* __restrict__ logits, const float* __restrict__ gate_b,
                                      int* __restrict__ counts, int* __restrict__ prefix,
                                      int* __restrict__ ctok, int* __restrict__ cslot,
                                      float* __restrict__ cwt) {
  int n = threadIdx.x;  // 1024 threads = 1 per token
  __shared__ int scnt[Ee];
  __shared__ int spre[Ee];
  __shared__ int soff[Ee];
  if (n < Ee) { scnt[n] = 0; soff[n] = 0; }
  __syncthreads();
  float sc[Ee], bi[Ee];
  #pragma unroll
  for (int e=0;e<Ee;e++){ float s = sigmoidf_(logits[n*Ee+e]); sc[e]=s; bi[e]=s+gate_b[e]; }
  int i0=0;
  #pragma unroll
  for (int e=1;e<Ee;e++) if (bi[e] > bi[i0]) i0=e;
  int i1=-1;
  #pragma unroll
  for (int e=0;e<Ee;e++){ if (e==i0) continue; if (i1<0 || bi[e] > bi[i1]) i1=e; }
  float w0=sc[i0], w1=sc[i1];
  float inv = 1.f/(w0+w1+1e-20f);
  w0*=inv; w1*=inv;
  atomicAdd(&scnt[i0],1);
  atomicAdd(&scnt[i1],1);
  __syncthreads();
  if (n == 0){ int s=0; for (int e=0;e<Ee;e++){ spre[e]=s; s+=scnt[e]; } }
  __syncthreads();
  int p0 = spre[i0] + atomicAdd(&soff[i0],1);
  ctok[p0]=n; cslot[p0]=0; cwt[p0]=w0;
  int p1 = spre[i1] + atomicAdd(&soff[i1],1);
  ctok[p1]=n; cslot[p1]=1; cwt[p1]=w1;
  ctok[NASSIGN+n]=n; cslot[NASSIGN+n]=2; cwt[NASSIGN+n]=1.f;
  if (n < Ee){ counts[n]=scnt[n]; prefix[n]=spre[n]; }
  if (n == 0){ counts[Ee]=Ntok; prefix[Ee]=NASSIGN; }
}

__global__ void final_kernel(const float* __restrict__ h, const __hip_bfloat16* __restrict__ routed,
                             float* __restrict__ out) {
  int idx = blockIdx.x*256 + threadIdx.x;
  if (idx >= Ntok*HIDD) return;
  int n = idx >> 10, c = idx & 1023;
  const __hip_bfloat16* rp = routed + (size_t)n*3*HIDD + c;
  out[idx] = h[idx] + bf2f(rp[0]) + bf2f(rp[HIDD]) + bf2f(rp[2*HIDD]);
}

// ---------------------------------------------------------------------------
extern "C" void kernel_launch(void* const* d_in, const int* in_sizes, int n_in,
                              void* d_out, int out_size, void* d_ws, size_t ws_size,
                              hipStream_t stream) {
  (void)in_sizes; (void)n_in; (void)out_size; (void)ws_size;
  const float* x        = (const float*)d_in[0];
  const float* norm1_w  = (const float*)d_in[1];
  const float* wq       = (const float*)d_in[2];
  const float* wk       = (const float*)d_in[3];
  const float* wv       = (const float*)d_in[4];
  const float* cq       = (const float*)d_in[5];
  const float* ck       = (const float*)d_in[6];
  const float* cv       = (const float*)d_in[7];
  const float* fa       = (const float*)d_in[8];
  const float* fb       = (const float*)d_in[9];
  const float* bp       = (const float*)d_in[10];
  const float* ga       = (const float*)d_in[11];
  const float* gb       = (const float*)d_in[12];
  const float* A_log    = (const float*)d_in[13];
  const float* dt_bias  = (const float*)d_in[14];
  const float* onorm_w  = (const float*)d_in[15];
  const float* wo       = (const float*)d_in[16];
  const float* norm2_w  = (const float*)d_in[17];
  const float* gate_w   = (const float*)d_in[18];
  const float* gate_b   = (const float*)d_in[19];
  const float* wg_e     = (const float*)d_in[20];
  const float* wu_e     = (const float*)d_in[21];
  const float* wd_e     = (const float*)d_in[22];
  const float* wg_s     = (const float*)d_in[23];
  const float* wu_s     = (const float*)d_in[24];
  const float* wd_s     = (const float*)d_in[25];
  float* out = (float*)d_out;

  char* base = (char*)d_ws;
  size_t off = 0;
  auto alloc = [&](size_t bytes)->char* {
    off = (off + 255) & ~(size_t)255;
    char* p = base + off; off += bytes; return p;
  };
  float* hbuf = (float*)alloc((size_t)Ntok*HIDD*4);
  size_t uStart = (off + 255) & ~(size_t)255;

  // ---- attention view ----
  off = uStart;
  __hip_bfloat16* xn      = (__hip_bfloat16*)alloc((size_t)Ntok*HIDD*2);
  __hip_bfloat16* xn_lo   = (__hip_bfloat16*)alloc((size_t)Ntok*HIDD*2);
  __hip_bfloat16* wqkv_t  = (__hip_bfloat16*)alloc((size_t)NQKV*HIDD*2);
  __hip_bfloat16* wqkv_lo = (__hip_bfloat16*)alloc((size_t)NQKV*HIDD*2);
  float*          qkvlin  = (float*)alloc((size_t)Ntok*3*Pp*4);
  float*          qc      = (float*)alloc((size_t)Ntok*Pp*4);
  float*          kc      = (float*)alloc((size_t)Ntok*Pp*4);
  float*          vc      = (float*)alloc((size_t)Ntok*Pp*4);
  float*          gbuf    = (float*)alloc((size_t)Ntok*Pp*4);
  float*          gatebuf = (float*)alloc((size_t)Ntok*Pp*4);
  float*          obuf    = (float*)alloc((size_t)Ntok*Pp*4);
  __hip_bfloat16* atmp12  = (__hip_bfloat16*)alloc((size_t)Ntok*2*Dd*2);
  float*          betab   = (float*)alloc((size_t)Ntok*Hh*4);
  __hip_bfloat16* obuf_hi = (__hip_bfloat16*)alloc((size_t)Ntok*Pp*2);
  __hip_bfloat16* obuf_lo = (__hip_bfloat16*)alloc((size_t)Ntok*Pp*2);
  __hip_bfloat16* wo_t    = (__hip_bfloat16*)alloc((size_t)HIDD*Pp*2);
  __hip_bfloat16* wo_lo   = (__hip_bfloat16*)alloc((size_t)HIDD*Pp*2);
  __hip_bfloat16* fbgb_t  = (__hip_bfloat16*)alloc((size_t)2048*128*2);

  // ---- moe view (overlaps attention view) ----
  off = uStart;
  __hip_bfloat16* hn      = (__hip_bfloat16*)alloc((size_t)Ntok*HIDD*2);
  float*          scores  = (float*)alloc((size_t)Ntok*Ee*4);
  int*            counts  = (int*)alloc(64);
  int*            prefix  = (int*)alloc(64);
  int*            ctok    = (int*)alloc((size_t)(NTOT+64)*4);
  int*            cslot   = (int*)alloc((size_t)(NTOT+64)*4);
  float*          cwt     = (float*)alloc((size_t)(NTOT+64)*4);
  __hip_bfloat16* egu_t   = (__hip_bfloat16*)alloc((size_t)9*2*Ii*HIDD*2);
  __hip_bfloat16* act     = (__hip_bfloat16*)alloc((size_t)NTOT*Ii*2);
  __hip_bfloat16* routed  = (__hip_bfloat16*)alloc((size_t)Ntok*3*HIDD*2);
  __hip_bfloat16* ed_t    = (__hip_bfloat16*)alloc((size_t)9*HIDD*Ii*2);

  dim3 blk(256);
  #define NO5 nullptr, nullptr, nullptr, nullptr, nullptr

  // ================= attention =================
  rms_beta_split_kernel<<<Ntok, blk, 0, stream>>>(x, norm1_w, bp, xn, xn_lo, betab, 1e-5f);
  trans_split6_kernel<<<dim3(32,32,6), blk, 0, stream>>>(wq, wk, wv, wo, fa, ga,
                                                         wqkv_t, wqkv_lo, wo_t, wo_lo);
  trans_fbgb_kernel<<<dim3(32,2,2), blk, 0, stream>>>(fb, gb, fbgb_t);

  // QKV + fg-stage1 fused (N=3200; fg epilogue -> atmp12 via resid ptr)
  gemm3_k<3,128><<<dim3(25,16,1), blk, 0, stream>>>(xn, xn_lo, wqkv_t, wqkv_lo, qkvlin,
                                                    Ntok, NQKV, HIDD, (const float*)atmp12);
  conv_norm_kernel<<<dim3(Ntok,3,1), blk, 0, stream>>>(qkvlin, cq, ck, cv, qc, kc, vc);
  gemm_k<8,0,128><<<dim3(16,16,1), blk, 0, stream>>>(atmp12, fbgb_t, gbuf, Ntok, 2048, 128, 2*Dd,
                                                     A_log, nullptr, nullptr,
                                                     (const int*)gatebuf, nullptr, dt_bias);
  scan_kernel<<<Bb*Hh*16, dim3(64), 0, stream>>>(qc, kc, vc, gbuf, betab, obuf);
  onorm_gate_split_kernel<<<(Ntok*Hh)/4, blk, 0, stream>>>(obuf, onorm_w, gatebuf, obuf_hi, obuf_lo);
  gemm3_k<2,64><<<dim3(16,16,1), blk, 0, stream>>>(obuf_hi, obuf_lo, wo_t, wo_lo, hbuf,
                                                   Ntok, HIDD, Pp, x);

  // ================= MoE (shared expert folded in as expert 8) =================
  moe_rms_scores_kernel<<<Ntok, blk, 0, stream>>>(hbuf, norm2_w, gate_w, hn, scores);
  router_compact_kernel<<<1, dim3(1024), 0, stream>>>(scores, gate_b, counts, prefix,
                                                      ctok, cslot, cwt);
  trans_expert_kernel<<<dim3(32,32,27), blk, 0, stream>>>(wg_e, wu_e, wg_s, wu_s, wd_e, wd_s,
                                                          egu_t, ed_t);
  gemm_k<6,0,128><<<dim3(12,16,9), blk, 0, stream>>>(hn, egu_t, act, Ntok, 2*Ii, HIDD, HIDD,
                                                     nullptr, counts, prefix, ctok, nullptr, nullptr);
  gemm_k<4,0,128><<<dim3(8,16,9), blk, 0, stream>>>(act, ed_t, routed, Ntok, HIDD, Ii, Ii,
                                                    nullptr, counts, prefix, ctok, cslot, cwt);

  final_kernel<<<(Ntok*HIDD+255)/256, blk, 0, stream>>>(hbuf, routed, out);
}

// Round 19
// 296.563 us; speedup vs baseline: 1.0225x; 1.0225x over previous
//
#include <hip/hip_runtime.h>
#include <hip/hip_bf16.h>
#include <math.h>

#define Bb 2
#define Tt 512
#define HIDD 1024
#define Hh 16
#define Dd 64
#define Pp 1024
#define Kc 4
#define Ee 8
#define Ii 768
#define Ntok (Bb*Tt)   // 1024
#define NASSIGN (2*Ntok)  // 2048
#define NTOT (NASSIGN + Ntok)  // 3072 incl shared
#define SCH 8
#define SNCH (Tt/SCH)  // 64
#define NQKV 3200      // 3072 qkv cols + 128 fg cols

typedef __attribute__((ext_vector_type(8))) short bf16x8;
typedef __attribute__((ext_vector_type(4))) float floatx4;

__device__ __forceinline__ float sigmoidf_(float x){ return 1.f/(1.f+expf(-x)); }
__device__ __forceinline__ float siluf_(float x){ return x/(1.f+expf(-x)); }
__device__ __forceinline__ float bf2f(__hip_bfloat16 b){ return __bfloat162float(b); }

__device__ __forceinline__ void async16(void* lds, const void* g) {
  __builtin_amdgcn_global_load_lds(
      (const __attribute__((address_space(1))) void*)g,
      (__attribute__((address_space(3))) void*)lds, 16, 0, 0);
}

template<int CTRL>
__device__ __forceinline__ float dpp_add(float x){
  int y = __builtin_amdgcn_update_dpp(0, __float_as_int(x), CTRL, 0xF, 0xF, true);
  return x + __int_as_float(y);
}

__device__ __forceinline__ void ds_read128(floatx4& d, const float* p){
  asm volatile("ds_read_b128 %0, %1"
    : "=v"(d)
    : "v"((const __attribute__((address_space(3))) float*)p));
}
__device__ __forceinline__ void ds_read32f(float& d, const float* p){
  asm volatile("ds_read_b32 %0, %1"
    : "=v"(d)
    : "v"((const __attribute__((address_space(3))) float*)p));
}

// ===== PREP fused: blocks 0..1023 rms+beta; 1024..7167 split-transpose wq/wk/wv/wo/fa/ga;
//       7168..7295 fbgb. Separate shared decls (no unioning). =====
__global__ __launch_bounds__(256)
void prep_kernel(const float* __restrict__ x, const float* __restrict__ w,
                 const float* __restrict__ bp,
                 __hip_bfloat16* __restrict__ xhi, __hip_bfloat16* __restrict__ xlo,
                 float* __restrict__ betab,
                 const float* __restrict__ wq, const float* __restrict__ wk,
                 const float* __restrict__ wv, const float* __restrict__ wo,
                 const float* __restrict__ fa, const float* __restrict__ ga,
                 __hip_bfloat16* __restrict__ qkv_hi, __hip_bfloat16* __restrict__ qkv_lo,
                 __hip_bfloat16* __restrict__ wo_hi, __hip_bfloat16* __restrict__ wo_lo,
                 const float* __restrict__ fb, const float* __restrict__ gb,
                 __hip_bfloat16* __restrict__ fbgb_dst) {
  __shared__ float red[4];
  __shared__ float redb[4][16];
  __shared__ float tile[32][33];
  int bid = blockIdx.x;
  if (bid < Ntok) {
    // ---- rms + beta (verbatim rms_beta_split_kernel body) ----
    int row = bid;
    const float* xr = x + (size_t)row*HIDD;
    float s = 0.f;
    for (int i = threadIdx.x; i < HIDD; i += 256){ float v = xr[i]; s += v*v; }
    #pragma unroll
    for (int off=32; off; off>>=1) s += __shfl_down(s, off, 64);
    if ((threadIdx.x & 63)==0) red[threadIdx.x>>6] = s;
    __syncthreads();
    float tot = red[0]+red[1]+red[2]+red[3];
    float sc = rsqrtf(tot/(float)HIDD + 1e-5f);
    float bacc[16] = {};
    for (int i = threadIdx.x; i < HIDD; i += 256) {
      float v = xr[i]*sc*w[i];
      __hip_bfloat16 h = __float2bfloat16(v);
      xhi[(size_t)row*HIDD+i] = h;
      xlo[(size_t)row*HIDD+i] = __float2bfloat16(v - bf2f(h));
      #pragma unroll
      for (int n=0;n<16;n++) bacc[n] += v * bp[i*16+n];
    }
    #pragma unroll
    for (int n=0;n<16;n++){
      #pragma unroll
      for (int off=32; off; off>>=1) bacc[n] += __shfl_down(bacc[n], off, 64);
    }
    if ((threadIdx.x & 63)==0){
      #pragma unroll
      for (int n=0;n<16;n++) redb[threadIdx.x>>6][n] = bacc[n];
    }
    __syncthreads();
    if (threadIdx.x < 16)
      betab[(size_t)row*16 + threadIdx.x] =
        sigmoidf_(redb[0][threadIdx.x]+redb[1][threadIdx.x]+redb[2][threadIdx.x]+redb[3][threadIdx.x]);
    return;
  }
  int tx = threadIdx.x & 31, ty0 = threadIdx.x >> 5;
  if (bid < Ntok + 6144) {
    // ---- split transpose (verbatim trans_split6 body; block remap) ----
    int b2 = bid - Ntok;
    int z = b2 >> 10;
    int r2 = b2 & 1023;
    int n0 = (r2 & 31)*32, k0 = (r2 >> 5)*32;
    const float* src; __hip_bfloat16* hi; __hip_bfloat16* lo; int N;
    if (z < 4) {
      src = (z==0)?wq:(z==1)?wk:(z==2)?wv:wo;
      hi = (z<3) ? qkv_hi + (size_t)z*Pp*HIDD : wo_hi;
      lo = (z<3) ? qkv_lo + (size_t)z*Pp*HIDD : wo_lo;
      N = 1024;
    } else {
      if (n0 >= 64) return;
      src = (z==4) ? fa : ga;
      hi = qkv_hi + (size_t)(3072 + (z-4)*64)*HIDD;
      lo = qkv_lo + (size_t)(3072 + (z-4)*64)*HIDD;
      N = 64;
    }
    #pragma unroll
    for (int j=0;j<4;j++){ int ty = ty0 + j*8; tile[ty][tx] = src[(size_t)(k0+ty)*N + n0+tx]; }
    __syncthreads();
    #pragma unroll
    for (int j=0;j<4;j++){
      int ty = ty0 + j*8;
      float v = tile[tx][ty];
      __hip_bfloat16 h = __float2bfloat16(v);
      hi[(size_t)(n0+ty)*HIDD + k0+tx] = h;
      lo[(size_t)(n0+ty)*HIDD + k0+tx] = __float2bfloat16(v - bf2f(h));
    }
    return;
  }
  // ---- fbgb (verbatim body; block remap) ----
  int b3 = bid - Ntok - 6144;        // 0..127
  int z = b3 >> 6;                    // 0/1
  int r3 = b3 & 63;
  int n0 = (r3 & 31)*32, k0 = (r3 >> 5)*32;
  const float* src = z ? gb : fb;
  #pragma unroll
  for (int j=0;j<4;j++){ int ty = ty0 + j*8; tile[ty][tx] = src[(size_t)(k0+ty)*Pp + n0+tx]; }
  __syncthreads();
  #pragma unroll
  for (int j=0;j<4;j++){
    int ty = ty0 + j*8;
    size_t row = (size_t)(z*1024 + n0+ty);
    fbgb_dst[row*128 + (z?64:0) + k0+tx] = __float2bfloat16(tile[tx][ty]);
    fbgb_dst[row*128 + (z?0:64) + k0+tx] = __float2bfloat16(0.f);
  }
}

// ====== merged expert weight transpose: z 0..17 up (interleaved), z 18..26 down ======
__global__ void trans_expert_kernel(const float* __restrict__ wg_e, const float* __restrict__ wu_e,
                                    const float* __restrict__ wg_s, const float* __restrict__ wu_s,
                                    const float* __restrict__ wd_e, const float* __restrict__ wd_s,
                                    __hip_bfloat16* __restrict__ up_dst, __hip_bfloat16* __restrict__ dn_dst) {
  int z = blockIdx.z;
  __shared__ float tile[32][33];
  int n0 = blockIdx.x*32, k0 = blockIdx.y*32;
  int tx = threadIdx.x & 31, ty0 = threadIdx.x >> 5;
  if (z < 18) {
    if (n0 >= Ii) return;
    int e = z >> 1, phase = z & 1;
    const float* src = (e < 8) ? ((phase ? wu_e : wg_e) + (size_t)e*HIDD*Ii)
                               : (phase ? wu_s : wg_s);
    __hip_bfloat16* dst = up_dst + (size_t)e*(2*Ii*HIDD);
    #pragma unroll
    for (int j=0;j<4;j++){ int ty = ty0 + j*8; tile[ty][tx] = src[(size_t)(k0+ty)*Ii + n0+tx]; }
    __syncthreads();
    #pragma unroll
    for (int j=0;j<4;j++){
      int ty = ty0 + j*8;
      dst[(size_t)(2*(n0+ty)+phase)*HIDD + k0+tx] = __float2bfloat16(tile[tx][ty]);
    }
  } else {
    if (k0 >= Ii) return;
    int e = z - 18;
    const float* src = (e < 8) ? wd_e + (size_t)e*Ii*HIDD : wd_s;
    __hip_bfloat16* dst = dn_dst + (size_t)e*HIDD*Ii;
    #pragma unroll
    for (int j=0;j<4;j++){ int ty = ty0 + j*8; tile[ty][tx] = src[(size_t)(k0+ty)*HIDD + n0+tx]; }
    __syncthreads();
    #pragma unroll
    for (int j=0;j<4;j++){ int ty = ty0 + j*8; dst[(size_t)(n0+ty)*Ii + k0+tx] = __float2bfloat16(tile[tx][ty]); }
  }
}

// ================= MFMA GEMM core: BM=64, BN = BND (64 or 128), 4 waves =================
__device__ __forceinline__ int lds_off(int row, int slot){
  return row*128 + (((slot ^ row)&7)<<4);
}

// MODE 4: expert scatter (routed [tok][3][N]). 6: expert GLU with INDIRECT A-gather via ctok.
// 8: fb|gb fused (cols<1024 g-transform -> C; else f32 -> (float*)ctok).
template<int MODE, int ACC, int BND>
__global__ __launch_bounds__(256)
void gemm_k(const __hip_bfloat16* __restrict__ A, const __hip_bfloat16* __restrict__ BT,
            void* __restrict__ C, int M, int N, int K, int lda, const float* __restrict__ resid,
            const int* __restrict__ counts, const int* __restrict__ prefix,
            const int* __restrict__ ctok, const int* __restrict__ cslot,
            const float* __restrict__ cwt) {
  constexpr int NF = BND/32;
  int Me = M;
  int moff = 0;
  if (MODE == 4 || MODE == 6) {
    int e = blockIdx.z;
    Me = counts[e]; moff = prefix[e];
    if (MODE == 4) A += (size_t)moff * lda;
    BT += (size_t)e * (size_t)N * K;
  }
  int row0 = blockIdx.y * 64;
  if (row0 >= Me) return;
  int col0 = blockIdx.x * BND;

  __shared__ __attribute__((aligned(16))) short As[64*64];
  __shared__ __attribute__((aligned(16))) short Bs[BND*64];
  __shared__ int sidx[64];
  const int lane = threadIdx.x & 63;
  const int w    = threadIdx.x >> 6;
  const int wr = w >> 1, wc = w & 1;
  const int srow = lane >> 3;
  const int sch  = (lane & 7) ^ (srow & 7);
  const int q = lane >> 4, r16 = lane & 15;

  if (MODE == 6) {
    if (threadIdx.x < 64) {
      int rr = row0 + threadIdx.x;
      sidx[threadIdx.x] = (rr < Me) ? ctok[moff + rr] : 0;
    }
    __syncthreads();
  }

  const __hip_bfloat16* Ag = A  + (size_t)row0 * lda;
  const __hip_bfloat16* Bg = BT + (size_t)col0 * K;

  floatx4 acc[2][NF] = {};

  for (int k0 = 0; k0 < K; k0 += 64) {
    #pragma unroll
    for (int ii = 0; ii < 2; ++ii) {
      const int inst = w + ii*4;
      const int r = inst*8 + srow;
      if (MODE == 6)
        async16((char*)As + inst*1024, A + (size_t)sidx[r]*lda + (size_t)(k0 + sch*8));
      else
        async16((char*)As + inst*1024, Ag + (size_t)r*lda + (size_t)(k0 + sch*8));
    }
    #pragma unroll
    for (int ii = 0; ii < BND/32; ++ii) {
      const int inst = w + ii*4;
      const int r = inst*8 + srow;
      async16((char*)Bs + inst*1024, Bg + (size_t)r*K + (size_t)(k0 + sch*8));
    }
    __syncthreads();
    #pragma unroll
    for (int kk = 0; kk < 2; ++kk) {
      int slot = kk*4 + q;
      bf16x8 a0 = *(const bf16x8*)((const char*)As + lds_off(wr*32 +      r16, slot));
      bf16x8 a1 = *(const bf16x8*)((const char*)As + lds_off(wr*32 + 16 + r16, slot));
      bf16x8 b[NF];
      #pragma unroll
      for (int ni=0; ni<NF; ++ni)
        b[ni] = *(const bf16x8*)((const char*)Bs + lds_off(wc*(BND/2) + ni*16 + r16, slot));
      #pragma unroll
      for (int ni=0; ni<NF; ++ni){
        acc[0][ni] = __builtin_amdgcn_mfma_f32_16x16x32_bf16(a0, b[ni], acc[0][ni], 0, 0, 0);
        acc[1][ni] = __builtin_amdgcn_mfma_f32_16x16x32_bf16(a1, b[ni], acc[1][ni], 0, 0, 0);
      }
    }
    __syncthreads();
  }

  #pragma unroll
  for (int mi = 0; mi < 2; ++mi) {
    #pragma unroll
    for (int r = 0; r < 4; ++r) {
      int grow = row0 + wr*32 + mi*16 + q*4 + r;
      if (grow >= Me) continue;
      #pragma unroll
      for (int ni = 0; ni < NF; ++ni) {
        int gcol = col0 + wc*(BND/2) + ni*16 + r16;
        float v = acc[mi][ni][r];
        if (MODE == 4) {
          int rc = moff + grow;
          int tok = ctok[rc], sl = cslot[rc];
          ((__hip_bfloat16*)C)[((size_t)tok*3 + sl)*N + gcol] = __float2bfloat16(cwt[rc]*v);
        } else if (MODE == 6) {
          float pv = __shfl_xor(v, 1, 64);
          if ((lane & 1) == 0) {
            float rglu = siluf_(v) * pv;
            ((__hip_bfloat16*)C)[(size_t)(moff+grow)*(N/2) + (gcol>>1)] = __float2bfloat16(rglu);
          }
        } else if (MODE == 8) {
          if (gcol < 1024) {
            int hh2 = gcol >> 6, d2 = gcol & 63;
            float t2 = v + cwt[hh2*64 + d2];
            float sp = (t2 > 20.f) ? t2 : log1pf(expf(t2));
            ((float*)C)[(size_t)grow*1024 + gcol] = expf(-expf(resid[hh2]) * sp);
          } else {
            ((float*)(size_t)ctok)[(size_t)grow*1024 + (gcol-1024)] = v;
          }
        }
      }
    }
  }
}

// 3-phase split-bf16 GEMM, merged staging.
// MODE 2: f32 + resid. 3: QKV+fg fused (col<3072 -> f32 qkvlin stride 3072;
//   col>=3072 -> bf16 atmp12 (via resid ptr) stride 128).
template<int MODE, int BND>
__global__ __launch_bounds__(256)
void gemm3_k(const __hip_bfloat16* __restrict__ Ahi, const __hip_bfloat16* __restrict__ Alo,
             const __hip_bfloat16* __restrict__ Bhi, const __hip_bfloat16* __restrict__ Blo,
             float* __restrict__ C, int M, int N, int K, const float* __restrict__ resid) {
  constexpr int NF = BND/32;
  int row0 = blockIdx.y * 64;
  int col0 = blockIdx.x * BND;

  __shared__ __attribute__((aligned(16))) short As[64*64];
  __shared__ __attribute__((aligned(16))) short Bs[2][BND*64];
  const int lane = threadIdx.x & 63;
  const int w    = threadIdx.x >> 6;
  const int wr = w >> 1, wc = w & 1;
  const int srow = lane >> 3;
  const int sch  = (lane & 7) ^ (srow & 7);
  const int q = lane >> 4, r16 = lane & 15;

  const __hip_bfloat16* Ag0 = Ahi + (size_t)row0 * K;
  const __hip_bfloat16* Ag1 = Alo + (size_t)row0 * K;
  const __hip_bfloat16* Bg0 = Bhi + (size_t)col0 * K;
  const __hip_bfloat16* Bg1 = Blo + (size_t)col0 * K;

  floatx4 acc[2][NF] = {};

  // phase A: Ahi * (Bhi + Blo)
  for (int k0 = 0; k0 < K; k0 += 64) {
    #pragma unroll
    for (int ii = 0; ii < 2; ++ii) {
      const int inst = w + ii*4;
      const int r = inst*8 + srow;
      async16((char*)As + inst*1024, Ag0 + (size_t)r*K + (size_t)(k0 + sch*8));
    }
    #pragma unroll
    for (int ii = 0; ii < BND/32; ++ii) {
      const int inst = w + ii*4;
      const int r = inst*8 + srow;
      async16((char*)Bs[0] + inst*1024, Bg0 + (size_t)r*K + (size_t)(k0 + sch*8));
      async16((char*)Bs[1] + inst*1024, Bg1 + (size_t)r*K + (size_t)(k0 + sch*8));
    }
    __syncthreads();
    #pragma unroll
    for (int kk = 0; kk < 2; ++kk) {
      int slot = kk*4 + q;
      bf16x8 a0 = *(const bf16x8*)((const char*)As + lds_off(wr*32 +      r16, slot));
      bf16x8 a1 = *(const bf16x8*)((const char*)As + lds_off(wr*32 + 16 + r16, slot));
      #pragma unroll
      for (int pb = 0; pb < 2; ++pb) {
        bf16x8 b[NF];
        #pragma unroll
        for (int ni=0; ni<NF; ++ni)
          b[ni] = *(const bf16x8*)((const char*)Bs[pb] + lds_off(wc*(BND/2) + ni*16 + r16, slot));
        #pragma unroll
        for (int ni=0; ni<NF; ++ni){
          acc[0][ni] = __builtin_amdgcn_mfma_f32_16x16x32_bf16(a0, b[ni], acc[0][ni], 0, 0, 0);
          acc[1][ni] = __builtin_amdgcn_mfma_f32_16x16x32_bf16(a1, b[ni], acc[1][ni], 0, 0, 0);
        }
      }
    }
    __syncthreads();
  }
  // phase B: Alo * Bhi
  for (int k0 = 0; k0 < K; k0 += 64) {
    #pragma unroll
    for (int ii = 0; ii < 2; ++ii) {
      const int inst = w + ii*4;
      const int r = inst*8 + srow;
      async16((char*)As + inst*1024, Ag1 + (size_t)r*K + (size_t)(k0 + sch*8));
    }
    #pragma unroll
    for (int ii = 0; ii < BND/32; ++ii) {
      const int inst = w + ii*4;
      const int r = inst*8 + srow;
      async16((char*)Bs[0] + inst*1024, Bg0 + (size_t)r*K + (size_t)(k0 + sch*8));
    }
    __syncthreads();
    #pragma unroll
    for (int kk = 0; kk < 2; ++kk) {
      int slot = kk*4 + q;
      bf16x8 a0 = *(const bf16x8*)((const char*)As + lds_off(wr*32 +      r16, slot));
      bf16x8 a1 = *(const bf16x8*)((const char*)As + lds_off(wr*32 + 16 + r16, slot));
      bf16x8 b[NF];
      #pragma unroll
      for (int ni=0; ni<NF; ++ni)
        b[ni] = *(const bf16x8*)((const char*)Bs[0] + lds_off(wc*(BND/2) + ni*16 + r16, slot));
      #pragma unroll
      for (int ni=0; ni<NF; ++ni){
        acc[0][ni] = __builtin_amdgcn_mfma_f32_16x16x32_bf16(a0, b[ni], acc[0][ni], 0, 0, 0);
        acc[1][ni] = __builtin_amdgcn_mfma_f32_16x16x32_bf16(a1, b[ni], acc[1][ni], 0, 0, 0);
      }
    }
    __syncthreads();
  }

  #pragma unroll
  for (int mi = 0; mi < 2; ++mi) {
    #pragma unroll
    for (int r = 0; r < 4; ++r) {
      int grow = row0 + wr*32 + mi*16 + q*4 + r;
      #pragma unroll
      for (int ni = 0; ni < NF; ++ni) {
        int gcol = col0 + wc*(BND/2) + ni*16 + r16;
        float v = acc[mi][ni][r];
        if (MODE == 3) {
          if (gcol < 3072)
            C[(size_t)grow*3072 + gcol] = v;
          else
            ((__hip_bfloat16*)(size_t)resid)[(size_t)grow*128 + (gcol-3072)] = __float2bfloat16(v);
        } else {
          if (MODE == 2) v += resid[(size_t)grow*N + gcol];
          C[(size_t)grow*N + gcol] = v;
        }
      }
    }
  }
}

// ================= fused causal dwconv(K=4) + SiLU + (L2 norm for q/k) =================
__global__ void conv_norm_kernel(const float* __restrict__ in,
                                 const float* __restrict__ cq, const float* __restrict__ ck,
                                 const float* __restrict__ cv,
                                 float* __restrict__ qc, float* __restrict__ kc,
                                 float* __restrict__ vc) {
  int tok = blockIdx.x;
  int mode = blockIdx.y;
  const float* w = (mode==0) ? cq : (mode==1) ? ck : cv;
  float* outp    = (mode==0) ? qc : (mode==1) ? kc : vc;
  int colOff = mode << 10;
  int t = threadIdx.x;
  int c0 = t*4;
  int tloc = tok & (Tt-1);

  float wv[4][4];
  #pragma unroll
  for (int i=0;i<4;i++){
    float4 w4 = ((const float4*)w)[c0+i];
    wv[i][0]=w4.x; wv[i][1]=w4.y; wv[i][2]=w4.z; wv[i][3]=w4.w;
  }
  float acc[4] = {0.f,0.f,0.f,0.f};
  #pragma unroll
  for (int j=0;j<Kc;j++){
    int tt = tloc - (Kc-1) + j;
    if (tt >= 0){
      float4 xv = *(const float4*)&in[(size_t)(tok-(Kc-1)+j)*3072 + colOff + c0];
      acc[0] += wv[0][j]*xv.x;
      acc[1] += wv[1][j]*xv.y;
      acc[2] += wv[2][j]*xv.z;
      acc[3] += wv[3][j]*xv.w;
    }
  }
  float val[4];
  #pragma unroll
  for (int i=0;i<4;i++) val[i] = siluf_(acc[i]);
  float scale = 1.f;
  if (mode < 2) {
    float ss = val[0]*val[0]+val[1]*val[1]+val[2]*val[2]+val[3]*val[3];
    ss += __shfl_xor(ss, 1, 64);
    ss += __shfl_xor(ss, 2, 64);
    ss += __shfl_xor(ss, 4, 64);
    ss += __shfl_xor(ss, 8, 64);
    scale = rsqrtf(ss/(float)Dd + 1e-6f) * ((mode==0) ? (1.f/64.f) : 0.125f);
  }
  float4 o4 = make_float4(val[0]*scale, val[1]*scale, val[2]*scale, val[3]*scale);
  *(float4*)&outp[(size_t)tok*Pp + c0] = o4;
}

// ===== fused: hn = rms(h)*w2 (bf16), router logits (fp32) =====
__global__ void moe_rms_scores_kernel(const float* __restrict__ h, const float* __restrict__ w2,
                                      const float* __restrict__ gw,
                                      __hip_bfloat16* __restrict__ hn, float* __restrict__ scores) {
  int row = blockIdx.x;
  const float* hr = h + (size_t)row*HIDD;
  float s = 0.f;
  for (int i = threadIdx.x; i < HIDD; i += 256){ float v = hr[i]; s += v*v; }
  #pragma unroll
  for (int off=32; off; off>>=1) s += __shfl_down(s, off, 64);
  __shared__ float red[4];
  if ((threadIdx.x & 63)==0) red[threadIdx.x>>6] = s;
  __syncthreads();
  float sc = rsqrtf((red[0]+red[1]+red[2]+red[3])/(float)HIDD + 1e-5f);
  float acc[Ee] = {};
  for (int i = threadIdx.x; i < HIDD; i += 256){
    float xv = hr[i]*sc*w2[i];
    hn[(size_t)row*HIDD + i] = __float2bfloat16(xv);
    #pragma unroll
    for (int e=0;e<Ee;e++) acc[e] += xv*gw[i*Ee+e];
  }
  #pragma unroll
  for (int e=0;e<Ee;e++){
    #pragma unroll
    for (int off=32; off; off>>=1) acc[e] += __shfl_down(acc[e], off, 64);
  }
  __shared__ float red2[4][Ee];
  if ((threadIdx.x & 63)==0){
    #pragma unroll
    for (int e=0;e<Ee;e++) red2[threadIdx.x>>6][e] = acc[e];
  }
  __syncthreads();
  if (threadIdx.x < Ee)
    scores[(size_t)row*Ee + threadIdx.x] =
      red2[0][threadIdx.x]+red2[1][threadIdx.x]+red2[2][threadIdx.x]+red2[3][threadIdx.x];
}

// ================= delta-rule scan v6 (79 us proven) =================
#define REGLOAD(bufi, tbase, K,G,Q,VV,BT) do { \
  const int _b = (bufi); const int _t0 = (tbase); \
  _Pragma("unroll") \
  for (int _i=0;_i<SCH;_i++){ \
    ds_read128(K[_i], &sk[_b][_i][kq*4]); \
    ds_read128(G[_i], &sg[_b][_i][kq*4]); \
    ds_read128(Q[_i], &sq[_b][_i][kq*4]); \
    ds_read32f(VV[_i], &sbv[_t0+_i][vi]); \
    ds_read32f(BT[_i], &sb[_t0+_i]); \
  } \
} while(0)

#define SSTEP(K,G,Q,VV,BT,_i,_t) do { \
  floatx4 k4=K[_i], g4=G[_i], q4=Q[_i]; \
  float vvv=VV[_i], bt=BT[_i]; \
  S0*=g4.x; S1*=g4.y; S2*=g4.z; S3*=g4.w; \
  float pred = S0*k4.x + S1*k4.y + S2*k4.z + S3*k4.w; \
  pred = dpp_add<0xB1>(pred); pred = dpp_add<0x4E>(pred); \
  pred = dpp_add<0x141>(pred); pred = dpp_add<0x140>(pred); \
  float upd = (vvv - pred) * bt; \
  S0 += k4.x*upd; S1 += k4.y*upd; S2 += k4.z*upd; S3 += k4.w*upd; \
  float acc = S0*q4.x + S1*q4.y + S2*q4.z + S3*q4.w; \
  acc = dpp_add<0xB1>(acc); acc = dpp_add<0x4E>(acc); \
  acc = dpp_add<0x141>(acc); acc = dpp_add<0x140>(acc); \
  if (kq == 0) so[_t][vi] = acc; \
} while(0)

#define SITER(c, KC,GC,QC,VC,BC, KN,GN,QN,VN,BN) do { \
  if ((c)+1 < SNCH) { \
    if ((c)+2 < SNCH) asm volatile("s_waitcnt vmcnt(6)" ::: "memory"); \
    else              asm volatile("s_waitcnt vmcnt(0)" ::: "memory"); \
    REGLOAD(((c)+1)%3, ((c)+1)*SCH, KN,GN,QN,VN,BN); \
    if ((c)+3 < SNCH) stage(((c)+3)*SCH, ((c)+3)%3); \
  } \
  _Pragma("unroll") \
  for (int _s=0;_s<SCH;_s++) SSTEP(KC,GC,QC,VC,BC,_s,(c)*SCH+_s); \
  asm volatile("s_waitcnt lgkmcnt(0)" ::: "memory"); \
  __builtin_amdgcn_sched_barrier(0); \
} while(0)

__global__ __launch_bounds__(64)
void scan_kernel(const float* __restrict__ q, const float* __restrict__ k,
                 const float* __restrict__ v, const float* __restrict__ g,
                 const float* __restrict__ beta, float* __restrict__ o) {
  const int vb = blockIdx.x & 15;
  const int hh = (blockIdx.x >> 4) & 15;
  const int b  = blockIdx.x >> 8;
  const int lane = threadIdx.x;
  const int kq = lane & 15;
  const int vi = lane >> 4;
  const int v0 = vb*4;
  const int rb = b*Tt;

  __shared__ __attribute__((aligned(16))) float sq[3][SCH][64];
  __shared__ __attribute__((aligned(16))) float sk[3][SCH][64];
  __shared__ __attribute__((aligned(16))) float sg[3][SCH][64];
  __shared__ __attribute__((aligned(16))) float sbv[Tt][4];
  __shared__ float sb[Tt];
  __shared__ __attribute__((aligned(16))) float so[Tt][4];

  #pragma unroll
  for (int i=0;i<Tt/64;i++)
    sb[i*64+lane] = beta[(size_t)(rb + i*64 + lane)*Hh + hh];
  asm volatile("s_waitcnt vmcnt(0)" ::: "memory");

  #pragma unroll
  for (int i=0;i<Tt/64;i++)
    async16(&sbv[i*64][0], v + (size_t)(rb + i*64 + lane)*Pp + hh*64 + v0);

  auto stage = [&](int t0, int buf) {
    const int srow = lane >> 4, sch4 = (lane & 15)*4;
    #pragma unroll
    for (int ii=0; ii<2; ++ii) {
      size_t gbase = (size_t)(rb + t0 + ii*4 + srow)*Pp + hh*64;
      async16(&sq[buf][ii*4][0], q + gbase + sch4);
      async16(&sk[buf][ii*4][0], k + gbase + sch4);
      async16(&sg[buf][ii*4][0], g + gbase + sch4);
    }
  };

  floatx4 Ka[SCH],Ga[SCH],Qa[SCH], Kb[SCH],Gb[SCH],Qb[SCH];
  float Va[SCH],Bta[SCH], Vb2[SCH],Btb[SCH];
  float S0=0.f,S1=0.f,S2=0.f,S3=0.f;

  stage(0, 0);
  stage(SCH, 1);
  asm volatile("s_waitcnt vmcnt(6)" ::: "memory");
  REGLOAD(0, 0, Ka,Ga,Qa,Va,Bta);
  stage(2*SCH, 2);
  asm volatile("s_waitcnt lgkmcnt(0)" ::: "memory");
  __builtin_amdgcn_sched_barrier(0);

  for (int cp = 0; cp < SNCH; cp += 2) {
    SITER(cp,   Ka,Ga,Qa,Va,Bta, Kb,Gb,Qb,Vb2,Btb);
    SITER(cp+1, Kb,Gb,Qb,Vb2,Btb, Ka,Ga,Qa,Va,Bta);
  }

  #pragma unroll
  for (int i=0;i<Tt/64;i++){
    int t = i*64 + lane;
    *(float4*)&o[(size_t)(rb+t)*Pp + hh*64 + v0] = *(const float4*)&so[t][0];
  }
}

// ================= o = rms(o)*w*sigmoid(gate) -> split hi/lo bf16 =================
__global__ void onorm_gate_split_kernel(const float* __restrict__ o, const float* __restrict__ w,
                                        const float* __restrict__ gate,
                                        __hip_bfloat16* __restrict__ hi, __hip_bfloat16* __restrict__ lo) {
  int row = blockIdx.x*4 + (threadIdx.x>>6);
  int lane = threadIdx.x & 63;
  size_t idx = (size_t)row*Dd + lane;
  float v = o[idx];
  float s = v*v;
  #pragma unroll
  for (int off=32; off; off>>=1) s += __shfl_xor(s, off, 64);
  float r = v * rsqrtf(s/(float)Dd + 1e-5f) * w[lane] * sigmoidf_(gate[idx]);
  __hip_bfloat16 h = __float2bfloat16(r);
  hi[idx] = h;
  lo[idx] = __float2bfloat16(r - bf2f(h));
}

// ===== fused router + compact + prefix + shared tail (single block, 1024 threads) =====
__global__ void router_compact_kernel(const float* __restrict__ logits, const float* __restrict__ gate_b,
                                      int* __restrict__ counts, int* __restrict__ prefix,
                                      int* __restrict__ ctok, int* __restrict__ cslot,
                                      float* __restrict__ cwt) {
  int n = threadIdx.x;  // 1024 threads = 1 per token
  __shared__ int scnt[Ee];
  __shared__ int spre[Ee];
  __shared__ int soff[Ee];
  if (n < Ee) { scnt[n] = 0; soff[n] = 0; }
  __syncthreads();
  float sc[Ee], bi[Ee];
  #pragma unroll
  for (int e=0;e<Ee;e++){ float s = sigmoidf_(logits[n*Ee+e]); sc[e]=s; bi[e]=s+gate_b[e]; }
  int i0=0;
  #pragma unroll
  for (int e=1;e<Ee;e++) if (bi[e] > bi[i0]) i0=e;
  int i1=-1;
  #pragma unroll
  for (int e=0;e<Ee;e++){ if (e==i0) continue; if (i1<0 || bi[e] > bi[i1]) i1=e; }
  float w0=sc[i0], w1=sc[i1];
  float inv = 1.f/(w0+w1+1e-20f);
  w0*=inv; w1*=inv;
  atomicAdd(&scnt[i0],1);
  atomicAdd(&scnt[i1],1);
  __syncthreads();
  if (n == 0){ int s=0; for (int e=0;e<Ee;e++){ spre[e]=s; s+=scnt[e]; } }
  __syncthreads();
  int p0 = spre[i0] + atomicAdd(&soff[i0],1);
  ctok[p0]=n; cslot[p0]=0; cwt[p0]=w0;
  int p1 = spre[i1] + atomicAdd(&soff[i1],1);
  ctok[p1]=n; cslot[p1]=1; cwt[p1]=w1;
  ctok[NASSIGN+n]=n; cslot[NASSIGN+n]=2; cwt[NASSIGN+n]=1.f;
  if (n < Ee){ counts[n]=scnt[n]; prefix[n]=spre[n]; }
  if (n == 0){ counts[Ee]=Ntok; prefix[Ee]=NASSIGN; }
}

__global__ void final_kernel(const float* __restrict__ h, const __hip_bfloat16* __restrict__ routed,
                             float* __restrict__ out) {
  int idx = blockIdx.x*256 + threadIdx.x;
  if (idx >= Ntok*HIDD) return;
  int n = idx >> 10, c = idx & 1023;
  const __hip_bfloat16* rp = routed + (size_t)n*3*HIDD + c;
  out[idx] = h[idx] + bf2f(rp[0]) + bf2f(rp[HIDD]) + bf2f(rp[2*HIDD]);
}

// ---------------------------------------------------------------------------
extern "C" void kernel_launch(void* const* d_in, const int* in_sizes, int n_in,
                              void* d_out, int out_size, void* d_ws, size_t ws_size,
                              hipStream_t stream) {
  (void)in_sizes; (void)n_in; (void)out_size; (void)ws_size;
  const float* x        = (const float*)d_in[0];
  const float* norm1_w  = (const float*)d_in[1];
  const float* wq       = (const float*)d_in[2];
  const float* wk       = (const float*)d_in[3];
  const float* wv       = (const float*)d_in[4];
  const float* cq       = (const float*)d_in[5];
  const float* ck       = (const float*)d_in[6];
  const float* cv       = (const float*)d_in[7];
  const float* fa       = (const float*)d_in[8];
  const float* fb       = (const float*)d_in[9];
  const float* bp       = (const float*)d_in[10];
  const float* ga       = (const float*)d_in[11];
  const float* gb       = (const float*)d_in[12];
  const float* A_log    = (const float*)d_in[13];
  const float* dt_bias  = (const float*)d_in[14];
  const float* onorm_w  = (const float*)d_in[15];
  const float* wo       = (const float*)d_in[16];
  const float* norm2_w  = (const float*)d_in[17];
  const float* gate_w   = (const float*)d_in[18];
  const float* gate_b   = (const float*)d_in[19];
  const float* wg_e     = (const float*)d_in[20];
  const float* wu_e     = (const float*)d_in[21];
  const float* wd_e     = (const float*)d_in[22];
  const float* wg_s     = (const float*)d_in[23];
  const float* wu_s     = (const float*)d_in[24];
  const float* wd_s     = (const float*)d_in[25];
  float* out = (float*)d_out;

  char* base = (char*)d_ws;
  size_t off = 0;
  auto alloc = [&](size_t bytes)->char* {
    off = (off + 255) & ~(size_t)255;
    char* p = base + off; off += bytes; return p;
  };
  float* hbuf = (float*)alloc((size_t)Ntok*HIDD*4);
  size_t uStart = (off + 255) & ~(size_t)255;

  // ---- attention view ----
  off = uStart;
  __hip_bfloat16* xn      = (__hip_bfloat16*)alloc((size_t)Ntok*HIDD*2);
  __hip_bfloat16* xn_lo   = (__hip_bfloat16*)alloc((size_t)Ntok*HIDD*2);
  __hip_bfloat16* wqkv_t  = (__hip_bfloat16*)alloc((size_t)NQKV*HIDD*2);
  __hip_bfloat16* wqkv_lo = (__hip_bfloat16*)alloc((size_t)NQKV*HIDD*2);
  float*          qkvlin  = (float*)alloc((size_t)Ntok*3*Pp*4);
  float*          qc      = (float*)alloc((size_t)Ntok*Pp*4);
  float*          kc      = (float*)alloc((size_t)Ntok*Pp*4);
  float*          vc      = (float*)alloc((size_t)Ntok*Pp*4);
  float*          gbuf    = (float*)alloc((size_t)Ntok*Pp*4);
  float*          gatebuf = (float*)alloc((size_t)Ntok*Pp*4);
  float*          obuf    = (float*)alloc((size_t)Ntok*Pp*4);
  __hip_bfloat16* atmp12  = (__hip_bfloat16*)alloc((size_t)Ntok*2*Dd*2);
  float*          betab   = (float*)alloc((size_t)Ntok*Hh*4);
  __hip_bfloat16* obuf_hi = (__hip_bfloat16*)alloc((size_t)Ntok*Pp*2);
  __hip_bfloat16* obuf_lo = (__hip_bfloat16*)alloc((size_t)Ntok*Pp*2);
  __hip_bfloat16* wo_t    = (__hip_bfloat16*)alloc((size_t)HIDD*Pp*2);
  __hip_bfloat16* wo_lo   = (__hip_bfloat16*)alloc((size_t)HIDD*Pp*2);
  __hip_bfloat16* fbgb_t  = (__hip_bfloat16*)alloc((size_t)2048*128*2);

  // ---- moe view (overlaps attention view) ----
  off = uStart;
  __hip_bfloat16* hn      = (__hip_bfloat16*)alloc((size_t)Ntok*HIDD*2);
  float*          scores  = (float*)alloc((size_t)Ntok*Ee*4);
  int*            counts  = (int*)alloc(64);
  int*            prefix  = (int*)alloc(64);
  int*            ctok    = (int*)alloc((size_t)(NTOT+64)*4);
  int*            cslot   = (int*)alloc((size_t)(NTOT+64)*4);
  float*          cwt     = (float*)alloc((size_t)(NTOT+64)*4);
  __hip_bfloat16* egu_t   = (__hip_bfloat16*)alloc((size_t)9*2*Ii*HIDD*2);
  __hip_bfloat16* act     = (__hip_bfloat16*)alloc((size_t)NTOT*Ii*2);
  __hip_bfloat16* routed  = (__hip_bfloat16*)alloc((size_t)Ntok*3*HIDD*2);
  __hip_bfloat16* ed_t    = (__hip_bfloat16*)alloc((size_t)9*HIDD*Ii*2);

  dim3 blk(256);

  // ================= attention =================
  prep_kernel<<<Ntok + 6144 + 128, blk, 0, stream>>>(x, norm1_w, bp, xn, xn_lo, betab,
                                                     wq, wk, wv, wo, fa, ga,
                                                     wqkv_t, wqkv_lo, wo_t, wo_lo,
                                                     fb, gb, fbgb_t);
  // QKV + fg-stage1 fused (N=3200; fg epilogue -> atmp12 via resid ptr)
  gemm3_k<3,128><<<dim3(25,16,1), blk, 0, stream>>>(xn, xn_lo, wqkv_t, wqkv_lo, qkvlin,
                                                    Ntok, NQKV, HIDD, (const float*)atmp12);
  conv_norm_kernel<<<dim3(Ntok,3,1), blk, 0, stream>>>(qkvlin, cq, ck, cv, qc, kc, vc);
  gemm_k<8,0,128><<<dim3(16,16,1), blk, 0, stream>>>(atmp12, fbgb_t, gbuf, Ntok, 2048, 128, 2*Dd,
                                                     A_log, nullptr, nullptr,
                                                     (const int*)gatebuf, nullptr, dt_bias);
  scan_kernel<<<Bb*Hh*16, dim3(64), 0, stream>>>(qc, kc, vc, gbuf, betab, obuf);
  onorm_gate_split_kernel<<<(Ntok*Hh)/4, blk, 0, stream>>>(obuf, onorm_w, gatebuf, obuf_hi, obuf_lo);
  gemm3_k<2,64><<<dim3(16,16,1), blk, 0, stream>>>(obuf_hi, obuf_lo, wo_t, wo_lo, hbuf,
                                                   Ntok, HIDD, Pp, x);

  // ================= MoE (shared expert folded in as expert 8) =================
  moe_rms_scores_kernel<<<Ntok, blk, 0, stream>>>(hbuf, norm2_w, gate_w, hn, scores);
  router_compact_kernel<<<1, dim3(1024), 0, stream>>>(scores, gate_b, counts, prefix,
                                                      ctok, cslot, cwt);
  trans_expert_kernel<<<dim3(32,32,27), blk, 0, stream>>>(wg_e, wu_e, wg_s, wu_s, wd_e, wd_s,
                                                          egu_t, ed_t);
  gemm_k<6,0,128><<<dim3(12,16,9), blk, 0, stream>>>(hn, egu_t, act, Ntok, 2*Ii, HIDD, HIDD,
                                                     nullptr, counts, prefix, ctok, nullptr, nullptr);
  gemm_k<4,0,128><<<dim3(8,16,9), blk, 0, stream>>>(act, ed_t, routed, Ntok, HIDD, Ii, Ii,
                                                    nullptr, counts, prefix, ctok, cslot, cwt);

  final_kernel<<<(Ntok*HIDD+255)/256, blk, 0, stream>>>(hbuf, routed, out);
}

// Round 20
// 291.344 us; speedup vs baseline: 1.0408x; 1.0179x over previous
//
#include <hip/hip_runtime.h>
#include <hip/hip_bf16.h>
#include <math.h>

#define Bb 2
#define Tt 512
#define HIDD 1024
#define Hh 16
#define Dd 64
#define Pp 1024
#define Kc 4
#define Ee 8
#define Ii 768
#define Ntok (Bb*Tt)   // 1024
#define NASSIGN (2*Ntok)  // 2048
#define NTOT (NASSIGN + Ntok)  // 3072 incl shared
#define SCH 8
#define SNCH (Tt/SCH)  // 64
#define NQKV 3200      // 3072 qkv cols + 128 fg cols

typedef __attribute__((ext_vector_type(8))) short bf16x8;
typedef __attribute__((ext_vector_type(4))) float floatx4;

__device__ __forceinline__ float sigmoidf_(float x){ return 1.f/(1.f+expf(-x)); }
__device__ __forceinline__ float siluf_(float x){ return x/(1.f+expf(-x)); }
__device__ __forceinline__ float bf2f(__hip_bfloat16 b){ return __bfloat162float(b); }

__device__ __forceinline__ void async16(void* lds, const void* g) {
  __builtin_amdgcn_global_load_lds(
      (const __attribute__((address_space(1))) void*)g,
      (__attribute__((address_space(3))) void*)lds, 16, 0, 0);
}

template<int CTRL>
__device__ __forceinline__ float dpp_add(float x){
  int y = __builtin_amdgcn_update_dpp(0, __float_as_int(x), CTRL, 0xF, 0xF, true);
  return x + __int_as_float(y);
}

__device__ __forceinline__ void ds_read128(floatx4& d, const float* p){
  asm volatile("ds_read_b128 %0, %1"
    : "=v"(d)
    : "v"((const __attribute__((address_space(3))) float*)p));
}
__device__ __forceinline__ void ds_read32f(float& d, const float* p){
  asm volatile("ds_read_b32 %0, %1"
    : "=v"(d)
    : "v"((const __attribute__((address_space(3))) float*)p));
}

// ===== PREP fused: blocks 0..1023 rms+beta; 1024..7167 split-transpose wq/wk/wv/wo/fa/ga;
//       7168..7295 fbgb. Separate shared decls (no unioning). =====
__global__ __launch_bounds__(256)
void prep_kernel(const float* __restrict__ x, const float* __restrict__ w,
                 const float* __restrict__ bp,
                 __hip_bfloat16* __restrict__ xhi, __hip_bfloat16* __restrict__ xlo,
                 float* __restrict__ betab,
                 const float* __restrict__ wq, const float* __restrict__ wk,
                 const float* __restrict__ wv, const float* __restrict__ wo,
                 const float* __restrict__ fa, const float* __restrict__ ga,
                 __hip_bfloat16* __restrict__ qkv_hi, __hip_bfloat16* __restrict__ qkv_lo,
                 __hip_bfloat16* __restrict__ wo_hi, __hip_bfloat16* __restrict__ wo_lo,
                 const float* __restrict__ fb, const float* __restrict__ gb,
                 __hip_bfloat16* __restrict__ fbgb_dst) {
  __shared__ float red[4];
  __shared__ float redb[4][16];
  __shared__ float tile[32][33];
  int bid = blockIdx.x;
  if (bid < Ntok) {
    int row = bid;
    const float* xr = x + (size_t)row*HIDD;
    float s = 0.f;
    for (int i = threadIdx.x; i < HIDD; i += 256){ float v = xr[i]; s += v*v; }
    #pragma unroll
    for (int off=32; off; off>>=1) s += __shfl_down(s, off, 64);
    if ((threadIdx.x & 63)==0) red[threadIdx.x>>6] = s;
    __syncthreads();
    float tot = red[0]+red[1]+red[2]+red[3];
    float sc = rsqrtf(tot/(float)HIDD + 1e-5f);
    float bacc[16] = {};
    for (int i = threadIdx.x; i < HIDD; i += 256) {
      float v = xr[i]*sc*w[i];
      __hip_bfloat16 h = __float2bfloat16(v);
      xhi[(size_t)row*HIDD+i] = h;
      xlo[(size_t)row*HIDD+i] = __float2bfloat16(v - bf2f(h));
      #pragma unroll
      for (int n=0;n<16;n++) bacc[n] += v * bp[i*16+n];
    }
    #pragma unroll
    for (int n=0;n<16;n++){
      #pragma unroll
      for (int off=32; off; off>>=1) bacc[n] += __shfl_down(bacc[n], off, 64);
    }
    if ((threadIdx.x & 63)==0){
      #pragma unroll
      for (int n=0;n<16;n++) redb[threadIdx.x>>6][n] = bacc[n];
    }
    __syncthreads();
    if (threadIdx.x < 16)
      betab[(size_t)row*16 + threadIdx.x] =
        sigmoidf_(redb[0][threadIdx.x]+redb[1][threadIdx.x]+redb[2][threadIdx.x]+redb[3][threadIdx.x]);
    return;
  }
  int tx = threadIdx.x & 31, ty0 = threadIdx.x >> 5;
  if (bid < Ntok + 6144) {
    int b2 = bid - Ntok;
    int z = b2 >> 10;
    int r2 = b2 & 1023;
    int n0 = (r2 & 31)*32, k0 = (r2 >> 5)*32;
    const float* src; __hip_bfloat16* hi; __hip_bfloat16* lo; int N;
    if (z < 4) {
      src = (z==0)?wq:(z==1)?wk:(z==2)?wv:wo;
      hi = (z<3) ? qkv_hi + (size_t)z*Pp*HIDD : wo_hi;
      lo = (z<3) ? qkv_lo + (size_t)z*Pp*HIDD : wo_lo;
      N = 1024;
    } else {
      if (n0 >= 64) return;
      src = (z==4) ? fa : ga;
      hi = qkv_hi + (size_t)(3072 + (z-4)*64)*HIDD;
      lo = qkv_lo + (size_t)(3072 + (z-4)*64)*HIDD;
      N = 64;
    }
    #pragma unroll
    for (int j=0;j<4;j++){ int ty = ty0 + j*8; tile[ty][tx] = src[(size_t)(k0+ty)*N + n0+tx]; }
    __syncthreads();
    #pragma unroll
    for (int j=0;j<4;j++){
      int ty = ty0 + j*8;
      float v = tile[tx][ty];
      __hip_bfloat16 h = __float2bfloat16(v);
      hi[(size_t)(n0+ty)*HIDD + k0+tx] = h;
      lo[(size_t)(n0+ty)*HIDD + k0+tx] = __float2bfloat16(v - bf2f(h));
    }
    return;
  }
  int b3 = bid - Ntok - 6144;        // 0..127
  int z = b3 >> 6;                    // 0/1
  int r3 = b3 & 63;
  int n0 = (r3 & 31)*32, k0 = (r3 >> 5)*32;
  const float* src = z ? gb : fb;
  #pragma unroll
  for (int j=0;j<4;j++){ int ty = ty0 + j*8; tile[ty][tx] = src[(size_t)(k0+ty)*Pp + n0+tx]; }
  __syncthreads();
  #pragma unroll
  for (int j=0;j<4;j++){
    int ty = ty0 + j*8;
    size_t row = (size_t)(z*1024 + n0+ty);
    fbgb_dst[row*128 + (z?64:0) + k0+tx] = __float2bfloat16(tile[tx][ty]);
    fbgb_dst[row*128 + (z?0:64) + k0+tx] = __float2bfloat16(0.f);
  }
}

// ===== MOE-PREP fused: blocks 0..1023 = rms(h)*w2 -> hn (bf16) + router logits (fp32);
//       blocks 1024.. = expert weight transpose (z 0..17 up interleaved, 18..26 down) =====
__global__ __launch_bounds__(256)
void moe_prep_kernel(const float* __restrict__ h, const float* __restrict__ w2,
                     const float* __restrict__ gw,
                     __hip_bfloat16* __restrict__ hn, float* __restrict__ scores,
                     const float* __restrict__ wg_e, const float* __restrict__ wu_e,
                     const float* __restrict__ wg_s, const float* __restrict__ wu_s,
                     const float* __restrict__ wd_e, const float* __restrict__ wd_s,
                     __hip_bfloat16* __restrict__ up_dst, __hip_bfloat16* __restrict__ dn_dst) {
  __shared__ float red[4];
  __shared__ float red2[4][Ee];
  __shared__ float tile[32][33];
  int bid = blockIdx.x;
  if (bid < Ntok) {
    // ---- moe_rms_scores body (verbatim) ----
    int row = bid;
    const float* hr = h + (size_t)row*HIDD;
    float s = 0.f;
    for (int i = threadIdx.x; i < HIDD; i += 256){ float v = hr[i]; s += v*v; }
    #pragma unroll
    for (int off=32; off; off>>=1) s += __shfl_down(s, off, 64);
    if ((threadIdx.x & 63)==0) red[threadIdx.x>>6] = s;
    __syncthreads();
    float sc = rsqrtf((red[0]+red[1]+red[2]+red[3])/(float)HIDD + 1e-5f);
    float acc[Ee] = {};
    for (int i = threadIdx.x; i < HIDD; i += 256){
      float xv = hr[i]*sc*w2[i];
      hn[(size_t)row*HIDD + i] = __float2bfloat16(xv);
      #pragma unroll
      for (int e=0;e<Ee;e++) acc[e] += xv*gw[i*Ee+e];
    }
    #pragma unroll
    for (int e=0;e<Ee;e++){
      #pragma unroll
      for (int off=32; off; off>>=1) acc[e] += __shfl_down(acc[e], off, 64);
    }
    if ((threadIdx.x & 63)==0){
      #pragma unroll
      for (int e=0;e<Ee;e++) red2[threadIdx.x>>6][e] = acc[e];
    }
    __syncthreads();
    if (threadIdx.x < Ee)
      scores[(size_t)row*Ee + threadIdx.x] =
        red2[0][threadIdx.x]+red2[1][threadIdx.x]+red2[2][threadIdx.x]+red2[3][threadIdx.x];
    return;
  }
  // ---- trans_expert body (block remap: z = b2/1024, n0=(b2&31)*32, k0=((b2%1024)>>5)*32) ----
  int b2 = bid - Ntok;
  int z = b2 >> 10;          // 0..26
  int r2 = b2 & 1023;
  int n0 = (r2 & 31)*32, k0 = (r2 >> 5)*32;
  int tx = threadIdx.x & 31, ty0 = threadIdx.x >> 5;
  if (z < 18) {
    if (n0 >= Ii) return;
    int e = z >> 1, phase = z & 1;
    const float* src = (e < 8) ? ((phase ? wu_e : wg_e) + (size_t)e*HIDD*Ii)
                               : (phase ? wu_s : wg_s);
    __hip_bfloat16* dst = up_dst + (size_t)e*(2*Ii*HIDD);
    #pragma unroll
    for (int j=0;j<4;j++){ int ty = ty0 + j*8; tile[ty][tx] = src[(size_t)(k0+ty)*Ii + n0+tx]; }
    __syncthreads();
    #pragma unroll
    for (int j=0;j<4;j++){
      int ty = ty0 + j*8;
      dst[(size_t)(2*(n0+ty)+phase)*HIDD + k0+tx] = __float2bfloat16(tile[tx][ty]);
    }
  } else {
    if (k0 >= Ii) return;
    int e = z - 18;
    const float* src = (e < 8) ? wd_e + (size_t)e*Ii*HIDD : wd_s;
    __hip_bfloat16* dst = dn_dst + (size_t)e*HIDD*Ii;
    #pragma unroll
    for (int j=0;j<4;j++){ int ty = ty0 + j*8; tile[ty][tx] = src[(size_t)(k0+ty)*HIDD + n0+tx]; }
    __syncthreads();
    #pragma unroll
    for (int j=0;j<4;j++){ int ty = ty0 + j*8; dst[(size_t)(n0+ty)*Ii + k0+tx] = __float2bfloat16(tile[tx][ty]); }
  }
}

// ================= MFMA GEMM core: BM=64, BN = BND (64 or 128), 4 waves =================
__device__ __forceinline__ int lds_off(int row, int slot){
  return row*128 + (((slot ^ row)&7)<<4);
}

// MODE 4: expert scatter (routed [tok][3][N]). 6: expert GLU with INDIRECT A-gather via ctok.
// 8: fb|gb fused (cols<1024 g-transform -> C; else f32 -> (float*)ctok).
template<int MODE, int ACC, int BND>
__global__ __launch_bounds__(256)
void gemm_k(const __hip_bfloat16* __restrict__ A, const __hip_bfloat16* __restrict__ BT,
            void* __restrict__ C, int M, int N, int K, int lda, const float* __restrict__ resid,
            const int* __restrict__ counts, const int* __restrict__ prefix,
            const int* __restrict__ ctok, const int* __restrict__ cslot,
            const float* __restrict__ cwt) {
  constexpr int NF = BND/32;
  int Me = M;
  int moff = 0;
  if (MODE == 4 || MODE == 6) {
    int e = blockIdx.z;
    Me = counts[e]; moff = prefix[e];
    if (MODE == 4) A += (size_t)moff * lda;
    BT += (size_t)e * (size_t)N * K;
  }
  int row0 = blockIdx.y * 64;
  if (row0 >= Me) return;
  int col0 = blockIdx.x * BND;

  __shared__ __attribute__((aligned(16))) short As[64*64];
  __shared__ __attribute__((aligned(16))) short Bs[BND*64];
  __shared__ int sidx[64];
  const int lane = threadIdx.x & 63;
  const int w    = threadIdx.x >> 6;
  const int wr = w >> 1, wc = w & 1;
  const int srow = lane >> 3;
  const int sch  = (lane & 7) ^ (srow & 7);
  const int q = lane >> 4, r16 = lane & 15;

  if (MODE == 6) {
    if (threadIdx.x < 64) {
      int rr = row0 + threadIdx.x;
      sidx[threadIdx.x] = (rr < Me) ? ctok[moff + rr] : 0;
    }
    __syncthreads();
  }

  const __hip_bfloat16* Ag = A  + (size_t)row0 * lda;
  const __hip_bfloat16* Bg = BT + (size_t)col0 * K;

  floatx4 acc[2][NF] = {};

  for (int k0 = 0; k0 < K; k0 += 64) {
    #pragma unroll
    for (int ii = 0; ii < 2; ++ii) {
      const int inst = w + ii*4;
      const int r = inst*8 + srow;
      if (MODE == 6)
        async16((char*)As + inst*1024, A + (size_t)sidx[r]*lda + (size_t)(k0 + sch*8));
      else
        async16((char*)As + inst*1024, Ag + (size_t)r*lda + (size_t)(k0 + sch*8));
    }
    #pragma unroll
    for (int ii = 0; ii < BND/32; ++ii) {
      const int inst = w + ii*4;
      const int r = inst*8 + srow;
      async16((char*)Bs + inst*1024, Bg + (size_t)r*K + (size_t)(k0 + sch*8));
    }
    __syncthreads();
    #pragma unroll
    for (int kk = 0; kk < 2; ++kk) {
      int slot = kk*4 + q;
      bf16x8 a0 = *(const bf16x8*)((const char*)As + lds_off(wr*32 +      r16, slot));
      bf16x8 a1 = *(const bf16x8*)((const char*)As + lds_off(wr*32 + 16 + r16, slot));
      bf16x8 b[NF];
      #pragma unroll
      for (int ni=0; ni<NF; ++ni)
        b[ni] = *(const bf16x8*)((const char*)Bs + lds_off(wc*(BND/2) + ni*16 + r16, slot));
      #pragma unroll
      for (int ni=0; ni<NF; ++ni){
        acc[0][ni] = __builtin_amdgcn_mfma_f32_16x16x32_bf16(a0, b[ni], acc[0][ni], 0, 0, 0);
        acc[1][ni] = __builtin_amdgcn_mfma_f32_16x16x32_bf16(a1, b[ni], acc[1][ni], 0, 0, 0);
      }
    }
    __syncthreads();
  }

  #pragma unroll
  for (int mi = 0; mi < 2; ++mi) {
    #pragma unroll
    for (int r = 0; r < 4; ++r) {
      int grow = row0 + wr*32 + mi*16 + q*4 + r;
      if (grow >= Me) continue;
      #pragma unroll
      for (int ni = 0; ni < NF; ++ni) {
        int gcol = col0 + wc*(BND/2) + ni*16 + r16;
        float v = acc[mi][ni][r];
        if (MODE == 4) {
          int rc = moff + grow;
          int tok = ctok[rc], sl = cslot[rc];
          ((__hip_bfloat16*)C)[((size_t)tok*3 + sl)*N + gcol] = __float2bfloat16(cwt[rc]*v);
        } else if (MODE == 6) {
          float pv = __shfl_xor(v, 1, 64);
          if ((lane & 1) == 0) {
            float rglu = siluf_(v) * pv;
            ((__hip_bfloat16*)C)[(size_t)(moff+grow)*(N/2) + (gcol>>1)] = __float2bfloat16(rglu);
          }
        } else if (MODE == 8) {
          if (gcol < 1024) {
            int hh2 = gcol >> 6, d2 = gcol & 63;
            float t2 = v + cwt[hh2*64 + d2];
            float sp = (t2 > 20.f) ? t2 : log1pf(expf(t2));
            ((float*)C)[(size_t)grow*1024 + gcol] = expf(-expf(resid[hh2]) * sp);
          } else {
            ((float*)(size_t)ctok)[(size_t)grow*1024 + (gcol-1024)] = v;
          }
        }
      }
    }
  }
}

// 3-phase split-bf16 GEMM, merged staging.
// MODE 2: f32 + resid. 3: QKV+fg fused (col<3072 -> f32 qkvlin stride 3072;
//   col>=3072 -> bf16 atmp12 (via resid ptr) stride 128).
template<int MODE, int BND>
__global__ __launch_bounds__(256)
void gemm3_k(const __hip_bfloat16* __restrict__ Ahi, const __hip_bfloat16* __restrict__ Alo,
             const __hip_bfloat16* __restrict__ Bhi, const __hip_bfloat16* __restrict__ Blo,
             float* __restrict__ C, int M, int N, int K, const float* __restrict__ resid) {
  constexpr int NF = BND/32;
  int row0 = blockIdx.y * 64;
  int col0 = blockIdx.x * BND;

  __shared__ __attribute__((aligned(16))) short As[64*64];
  __shared__ __attribute__((aligned(16))) short Bs[2][BND*64];
  const int lane = threadIdx.x & 63;
  const int w    = threadIdx.x >> 6;
  const int wr = w >> 1, wc = w & 1;
  const int srow = lane >> 3;
  const int sch  = (lane & 7) ^ (srow & 7);
  const int q = lane >> 4, r16 = lane & 15;

  const __hip_bfloat16* Ag0 = Ahi + (size_t)row0 * K;
  const __hip_bfloat16* Ag1 = Alo + (size_t)row0 * K;
  const __hip_bfloat16* Bg0 = Bhi + (size_t)col0 * K;
  const __hip_bfloat16* Bg1 = Blo + (size_t)col0 * K;

  floatx4 acc[2][NF] = {};

  // phase A: Ahi * (Bhi + Blo)
  for (int k0 = 0; k0 < K; k0 += 64) {
    #pragma unroll
    for (int ii = 0; ii < 2; ++ii) {
      const int inst = w + ii*4;
      const int r = inst*8 + srow;
      async16((char*)As + inst*1024, Ag0 + (size_t)r*K + (size_t)(k0 + sch*8));
    }
    #pragma unroll
    for (int ii = 0; ii < BND/32; ++ii) {
      const int inst = w + ii*4;
      const int r = inst*8 + srow;
      async16((char*)Bs[0] + inst*1024, Bg0 + (size_t)r*K + (size_t)(k0 + sch*8));
      async16((char*)Bs[1] + inst*1024, Bg1 + (size_t)r*K + (size_t)(k0 + sch*8));
    }
    __syncthreads();
    #pragma unroll
    for (int kk = 0; kk < 2; ++kk) {
      int slot = kk*4 + q;
      bf16x8 a0 = *(const bf16x8*)((const char*)As + lds_off(wr*32 +      r16, slot));
      bf16x8 a1 = *(const bf16x8*)((const char*)As + lds_off(wr*32 + 16 + r16, slot));
      #pragma unroll
      for (int pb = 0; pb < 2; ++pb) {
        bf16x8 b[NF];
        #pragma unroll
        for (int ni=0; ni<NF; ++ni)
          b[ni] = *(const bf16x8*)((const char*)Bs[pb] + lds_off(wc*(BND/2) + ni*16 + r16, slot));
        #pragma unroll
        for (int ni=0; ni<NF; ++ni){
          acc[0][ni] = __builtin_amdgcn_mfma_f32_16x16x32_bf16(a0, b[ni], acc[0][ni], 0, 0, 0);
          acc[1][ni] = __builtin_amdgcn_mfma_f32_16x16x32_bf16(a1, b[ni], acc[1][ni], 0, 0, 0);
        }
      }
    }
    __syncthreads();
  }
  // phase B: Alo * Bhi
  for (int k0 = 0; k0 < K; k0 += 64) {
    #pragma unroll
    for (int ii = 0; ii < 2; ++ii) {
      const int inst = w + ii*4;
      const int r = inst*8 + srow;
      async16((char*)As + inst*1024, Ag1 + (size_t)r*K + (size_t)(k0 + sch*8));
    }
    #pragma unroll
    for (int ii = 0; ii < BND/32; ++ii) {
      const int inst = w + ii*4;
      const int r = inst*8 + srow;
      async16((char*)Bs[0] + inst*1024, Bg0 + (size_t)r*K + (size_t)(k0 + sch*8));
    }
    __syncthreads();
    #pragma unroll
    for (int kk = 0; kk < 2; ++kk) {
      int slot = kk*4 + q;
      bf16x8 a0 = *(const bf16x8*)((const char*)As + lds_off(wr*32 +      r16, slot));
      bf16x8 a1 = *(const bf16x8*)((const char*)As + lds_off(wr*32 + 16 + r16, slot));
      bf16x8 b[NF];
      #pragma unroll
      for (int ni=0; ni<NF; ++ni)
        b[ni] = *(const bf16x8*)((const char*)Bs[0] + lds_off(wc*(BND/2) + ni*16 + r16, slot));
      #pragma unroll
      for (int ni=0; ni<NF; ++ni){
        acc[0][ni] = __builtin_amdgcn_mfma_f32_16x16x32_bf16(a0, b[ni], acc[0][ni], 0, 0, 0);
        acc[1][ni] = __builtin_amdgcn_mfma_f32_16x16x32_bf16(a1, b[ni], acc[1][ni], 0, 0, 0);
      }
    }
    __syncthreads();
  }

  #pragma unroll
  for (int mi = 0; mi < 2; ++mi) {
    #pragma unroll
    for (int r = 0; r < 4; ++r) {
      int grow = row0 + wr*32 + mi*16 + q*4 + r;
      #pragma unroll
      for (int ni = 0; ni < NF; ++ni) {
        int gcol = col0 + wc*(BND/2) + ni*16 + r16;
        float v = acc[mi][ni][r];
        if (MODE == 3) {
          if (gcol < 3072)
            C[(size_t)grow*3072 + gcol] = v;
          else
            ((__hip_bfloat16*)(size_t)resid)[(size_t)grow*128 + (gcol-3072)] = __float2bfloat16(v);
        } else {
          if (MODE == 2) v += resid[(size_t)grow*N + gcol];
          C[(size_t)grow*N + gcol] = v;
        }
      }
    }
  }
}

// ================= fused causal dwconv(K=4) + SiLU + (L2 norm for q/k) =================
__global__ void conv_norm_kernel(const float* __restrict__ in,
                                 const float* __restrict__ cq, const float* __restrict__ ck,
                                 const float* __restrict__ cv,
                                 float* __restrict__ qc, float* __restrict__ kc,
                                 float* __restrict__ vc) {
  int tok = blockIdx.x;
  int mode = blockIdx.y;
  const float* w = (mode==0) ? cq : (mode==1) ? ck : cv;
  float* outp    = (mode==0) ? qc : (mode==1) ? kc : vc;
  int colOff = mode << 10;
  int t = threadIdx.x;
  int c0 = t*4;
  int tloc = tok & (Tt-1);

  float wv[4][4];
  #pragma unroll
  for (int i=0;i<4;i++){
    float4 w4 = ((const float4*)w)[c0+i];
    wv[i][0]=w4.x; wv[i][1]=w4.y; wv[i][2]=w4.z; wv[i][3]=w4.w;
  }
  float acc[4] = {0.f,0.f,0.f,0.f};
  #pragma unroll
  for (int j=0;j<Kc;j++){
    int tt = tloc - (Kc-1) + j;
    if (tt >= 0){
      float4 xv = *(const float4*)&in[(size_t)(tok-(Kc-1)+j)*3072 + colOff + c0];
      acc[0] += wv[0][j]*xv.x;
      acc[1] += wv[1][j]*xv.y;
      acc[2] += wv[2][j]*xv.z;
      acc[3] += wv[3][j]*xv.w;
    }
  }
  float val[4];
  #pragma unroll
  for (int i=0;i<4;i++) val[i] = siluf_(acc[i]);
  float scale = 1.f;
  if (mode < 2) {
    float ss = val[0]*val[0]+val[1]*val[1]+val[2]*val[2]+val[3]*val[3];
    ss += __shfl_xor(ss, 1, 64);
    ss += __shfl_xor(ss, 2, 64);
    ss += __shfl_xor(ss, 4, 64);
    ss += __shfl_xor(ss, 8, 64);
    scale = rsqrtf(ss/(float)Dd + 1e-6f) * ((mode==0) ? (1.f/64.f) : 0.125f);
  }
  float4 o4 = make_float4(val[0]*scale, val[1]*scale, val[2]*scale, val[3]*scale);
  *(float4*)&outp[(size_t)tok*Pp + c0] = o4;
}

// ================= delta-rule scan v6 (79 us proven) =================
#define REGLOAD(bufi, tbase, K,G,Q,VV,BT) do { \
  const int _b = (bufi); const int _t0 = (tbase); \
  _Pragma("unroll") \
  for (int _i=0;_i<SCH;_i++){ \
    ds_read128(K[_i], &sk[_b][_i][kq*4]); \
    ds_read128(G[_i], &sg[_b][_i][kq*4]); \
    ds_read128(Q[_i], &sq[_b][_i][kq*4]); \
    ds_read32f(VV[_i], &sbv[_t0+_i][vi]); \
    ds_read32f(BT[_i], &sb[_t0+_i]); \
  } \
} while(0)

#define SSTEP(K,G,Q,VV,BT,_i,_t) do { \
  floatx4 k4=K[_i], g4=G[_i], q4=Q[_i]; \
  float vvv=VV[_i], bt=BT[_i]; \
  S0*=g4.x; S1*=g4.y; S2*=g4.z; S3*=g4.w; \
  float pred = S0*k4.x + S1*k4.y + S2*k4.z + S3*k4.w; \
  pred = dpp_add<0xB1>(pred); pred = dpp_add<0x4E>(pred); \
  pred = dpp_add<0x141>(pred); pred = dpp_add<0x140>(pred); \
  float upd = (vvv - pred) * bt; \
  S0 += k4.x*upd; S1 += k4.y*upd; S2 += k4.z*upd; S3 += k4.w*upd; \
  float acc = S0*q4.x + S1*q4.y + S2*q4.z + S3*q4.w; \
  acc = dpp_add<0xB1>(acc); acc = dpp_add<0x4E>(acc); \
  acc = dpp_add<0x141>(acc); acc = dpp_add<0x140>(acc); \
  if (kq == 0) so[_t][vi] = acc; \
} while(0)

#define SITER(c, KC,GC,QC,VC,BC, KN,GN,QN,VN,BN) do { \
  if ((c)+1 < SNCH) { \
    if ((c)+2 < SNCH) asm volatile("s_waitcnt vmcnt(6)" ::: "memory"); \
    else              asm volatile("s_waitcnt vmcnt(0)" ::: "memory"); \
    REGLOAD(((c)+1)%3, ((c)+1)*SCH, KN,GN,QN,VN,BN); \
    if ((c)+3 < SNCH) stage(((c)+3)*SCH, ((c)+3)%3); \
  } \
  _Pragma("unroll") \
  for (int _s=0;_s<SCH;_s++) SSTEP(KC,GC,QC,VC,BC,_s,(c)*SCH+_s); \
  asm volatile("s_waitcnt lgkmcnt(0)" ::: "memory"); \
  __builtin_amdgcn_sched_barrier(0); \
} while(0)

__global__ __launch_bounds__(64)
void scan_kernel(const float* __restrict__ q, const float* __restrict__ k,
                 const float* __restrict__ v, const float* __restrict__ g,
                 const float* __restrict__ beta, float* __restrict__ o) {
  const int vb = blockIdx.x & 15;
  const int hh = (blockIdx.x >> 4) & 15;
  const int b  = blockIdx.x >> 8;
  const int lane = threadIdx.x;
  const int kq = lane & 15;
  const int vi = lane >> 4;
  const int v0 = vb*4;
  const int rb = b*Tt;

  __shared__ __attribute__((aligned(16))) float sq[3][SCH][64];
  __shared__ __attribute__((aligned(16))) float sk[3][SCH][64];
  __shared__ __attribute__((aligned(16))) float sg[3][SCH][64];
  __shared__ __attribute__((aligned(16))) float sbv[Tt][4];
  __shared__ float sb[Tt];
  __shared__ __attribute__((aligned(16))) float so[Tt][4];

  #pragma unroll
  for (int i=0;i<Tt/64;i++)
    sb[i*64+lane] = beta[(size_t)(rb + i*64 + lane)*Hh + hh];
  asm volatile("s_waitcnt vmcnt(0)" ::: "memory");

  #pragma unroll
  for (int i=0;i<Tt/64;i++)
    async16(&sbv[i*64][0], v + (size_t)(rb + i*64 + lane)*Pp + hh*64 + v0);

  auto stage = [&](int t0, int buf) {
    const int srow = lane >> 4, sch4 = (lane & 15)*4;
    #pragma unroll
    for (int ii=0; ii<2; ++ii) {
      size_t gbase = (size_t)(rb + t0 + ii*4 + srow)*Pp + hh*64;
      async16(&sq[buf][ii*4][0], q + gbase + sch4);
      async16(&sk[buf][ii*4][0], k + gbase + sch4);
      async16(&sg[buf][ii*4][0], g + gbase + sch4);
    }
  };

  floatx4 Ka[SCH],Ga[SCH],Qa[SCH], Kb[SCH],Gb[SCH],Qb[SCH];
  float Va[SCH],Bta[SCH], Vb2[SCH],Btb[SCH];
  float S0=0.f,S1=0.f,S2=0.f,S3=0.f;

  stage(0, 0);
  stage(SCH, 1);
  asm volatile("s_waitcnt vmcnt(6)" ::: "memory");
  REGLOAD(0, 0, Ka,Ga,Qa,Va,Bta);
  stage(2*SCH, 2);
  asm volatile("s_waitcnt lgkmcnt(0)" ::: "memory");
  __builtin_amdgcn_sched_barrier(0);

  for (int cp = 0; cp < SNCH; cp += 2) {
    SITER(cp,   Ka,Ga,Qa,Va,Bta, Kb,Gb,Qb,Vb2,Btb);
    SITER(cp+1, Kb,Gb,Qb,Vb2,Btb, Ka,Ga,Qa,Va,Bta);
  }

  #pragma unroll
  for (int i=0;i<Tt/64;i++){
    int t = i*64 + lane;
    *(float4*)&o[(size_t)(rb+t)*Pp + hh*64 + v0] = *(const float4*)&so[t][0];
  }
}

// ================= o = rms(o)*w*sigmoid(gate) -> split hi/lo bf16 =================
__global__ void onorm_gate_split_kernel(const float* __restrict__ o, const float* __restrict__ w,
                                        const float* __restrict__ gate,
                                        __hip_bfloat16* __restrict__ hi, __hip_bfloat16* __restrict__ lo) {
  int row = blockIdx.x*4 + (threadIdx.x>>6);
  int lane = threadIdx.x & 63;
  size_t idx = (size_t)row*Dd + lane;
  float v = o[idx];
  float s = v*v;
  #pragma unroll
  for (int off=32; off; off>>=1) s += __shfl_xor(s, off, 64);
  float r = v * rsqrtf(s/(float)Dd + 1e-5f) * w[lane] * sigmoidf_(gate[idx]);
  __hip_bfloat16 h = __float2bfloat16(r);
  hi[idx] = h;
  lo[idx] = __float2bfloat16(r - bf2f(h));
}

// ===== fused router + compact + prefix + shared tail (single block, 1024 threads) =====
__global__ void router_compact_kernel(const float* __restrict__ logits, const float* __restrict__ gate_b,
                                      int* __restrict__ counts, int* __restrict__ prefix,
                                      int* __restrict__ ctok, int* __restrict__ cslot,
                                      float* __restrict__ cwt) {
  int n = threadIdx.x;  // 1024 threads = 1 per token
  __shared__ int scnt[Ee];
  __shared__ int spre[Ee];
  __shared__ int soff[Ee];
  if (n < Ee) { scnt[n] = 0; soff[n] = 0; }
  __syncthreads();
  float sc[Ee], bi[Ee];
  #pragma unroll
  for (int e=0;e<Ee;e++){ float s = sigmoidf_(logits[n*Ee+e]); sc[e]=s; bi[e]=s+gate_b[e]; }
  int i0=0;
  #pragma unroll
  for (int e=1;e<Ee;e++) if (bi[e] > bi[i0]) i0=e;
  int i1=-1;
  #pragma unroll
  for (int e=0;e<Ee;e++){ if (e==i0) continue; if (i1<0 || bi[e] > bi[i1]) i1=e; }
  float w0=sc[i0], w1=sc[i1];
  float inv = 1.f/(w0+w1+1e-20f);
  w0*=inv; w1*=inv;
  atomicAdd(&scnt[i0],1);
  atomicAdd(&scnt[i1],1);
  __syncthreads();
  if (n == 0){ int s=0; for (int e=0;e<Ee;e++){ spre[e]=s; s+=scnt[e]; } }
  __syncthreads();
  int p0 = spre[i0] + atomicAdd(&soff[i0],1);
  ctok[p0]=n; cslot[p0]=0; cwt[p0]=w0;
  int p1 = spre[i1] + atomicAdd(&soff[i1],1);
  ctok[p1]=n; cslot[p1]=1; cwt[p1]=w1;
  ctok[NASSIGN+n]=n; cslot[NASSIGN+n]=2; cwt[NASSIGN+n]=1.f;
  if (n < Ee){ counts[n]=scnt[n]; prefix[n]=spre[n]; }
  if (n == 0){ counts[Ee]=Ntok; prefix[Ee]=NASSIGN; }
}

__global__ void final_kernel(const float* __restrict__ h, const __hip_bfloat16* __restrict__ routed,
                             float* __restrict__ out) {
  int idx = blockIdx.x*256 + threadIdx.x;
  if (idx >= Ntok*HIDD) return;
  int n = idx >> 10, c = idx & 1023;
  const __hip_bfloat16* rp = routed + (size_t)n*3*HIDD + c;
  out[idx] = h[idx] + bf2f(rp[0]) + bf2f(rp[HIDD]) + bf2f(rp[2*HIDD]);
}

// ---------------------------------------------------------------------------
extern "C" void kernel_launch(void* const* d_in, const int* in_sizes, int n_in,
                              void* d_out, int out_size, void* d_ws, size_t ws_size,
                              hipStream_t stream) {
  (void)in_sizes; (void)n_in; (void)out_size; (void)ws_size;
  const float* x        = (const float*)d_in[0];
  const float* norm1_w  = (const float*)d_in[1];
  const float* wq       = (const float*)d_in[2];
  const float* wk       = (const float*)d_in[3];
  const float* wv       = (const float*)d_in[4];
  const float* cq       = (const float*)d_in[5];
  const float* ck       = (const float*)d_in[6];
  const float* cv       = (const float*)d_in[7];
  const float* fa       = (const float*)d_in[8];
  const float* fb       = (const float*)d_in[9];
  const float* bp       = (const float*)d_in[10];
  const float* ga       = (const float*)d_in[11];
  const float* gb       = (const float*)d_in[12];
  const float* A_log    = (const float*)d_in[13];
  const float* dt_bias  = (const float*)d_in[14];
  const float* onorm_w  = (const float*)d_in[15];
  const float* wo       = (const float*)d_in[16];
  const float* norm2_w  = (const float*)d_in[17];
  const float* gate_w   = (const float*)d_in[18];
  const float* gate_b   = (const float*)d_in[19];
  const float* wg_e     = (const float*)d_in[20];
  const float* wu_e     = (const float*)d_in[21];
  const float* wd_e     = (const float*)d_in[22];
  const float* wg_s     = (const float*)d_in[23];
  const float* wu_s     = (const float*)d_in[24];
  const float* wd_s     = (const float*)d_in[25];
  float* out = (float*)d_out;

  char* base = (char*)d_ws;
  size_t off = 0;
  auto alloc = [&](size_t bytes)->char* {
    off = (off + 255) & ~(size_t)255;
    char* p = base + off; off += bytes; return p;
  };
  float* hbuf = (float*)alloc((size_t)Ntok*HIDD*4);
  size_t uStart = (off + 255) & ~(size_t)255;

  // ---- attention view ----
  off = uStart;
  __hip_bfloat16* xn      = (__hip_bfloat16*)alloc((size_t)Ntok*HIDD*2);
  __hip_bfloat16* xn_lo   = (__hip_bfloat16*)alloc((size_t)Ntok*HIDD*2);
  __hip_bfloat16* wqkv_t  = (__hip_bfloat16*)alloc((size_t)NQKV*HIDD*2);
  __hip_bfloat16* wqkv_lo = (__hip_bfloat16*)alloc((size_t)NQKV*HIDD*2);
  float*          qkvlin  = (float*)alloc((size_t)Ntok*3*Pp*4);
  float*          qc      = (float*)alloc((size_t)Ntok*Pp*4);
  float*          kc      = (float*)alloc((size_t)Ntok*Pp*4);
  float*          vc      = (float*)alloc((size_t)Ntok*Pp*4);
  float*          gbuf    = (float*)alloc((size_t)Ntok*Pp*4);
  float*          gatebuf = (float*)alloc((size_t)Ntok*Pp*4);
  float*          obuf    = (float*)alloc((size_t)Ntok*Pp*4);
  __hip_bfloat16* atmp12  = (__hip_bfloat16*)alloc((size_t)Ntok*2*Dd*2);
  float*          betab   = (float*)alloc((size_t)Ntok*Hh*4);
  __hip_bfloat16* obuf_hi = (__hip_bfloat16*)alloc((size_t)Ntok*Pp*2);
  __hip_bfloat16* obuf_lo = (__hip_bfloat16*)alloc((size_t)Ntok*Pp*2);
  __hip_bfloat16* wo_t    = (__hip_bfloat16*)alloc((size_t)HIDD*Pp*2);
  __hip_bfloat16* wo_lo   = (__hip_bfloat16*)alloc((size_t)HIDD*Pp*2);
  __hip_bfloat16* fbgb_t  = (__hip_bfloat16*)alloc((size_t)2048*128*2);

  // ---- moe view (overlaps attention view) ----
  off = uStart;
  __hip_bfloat16* hn      = (__hip_bfloat16*)alloc((size_t)Ntok*HIDD*2);
  float*          scores  = (float*)alloc((size_t)Ntok*Ee*4);
  int*            counts  = (int*)alloc(64);
  int*            prefix  = (int*)alloc(64);
  int*            ctok    = (int*)alloc((size_t)(NTOT+64)*4);
  int*            cslot   = (int*)alloc((size_t)(NTOT+64)*4);
  float*          cwt     = (float*)alloc((size_t)(NTOT+64)*4);
  __hip_bfloat16* egu_t   = (__hip_bfloat16*)alloc((size_t)9*2*Ii*HIDD*2);
  __hip_bfloat16* act     = (__hip_bfloat16*)alloc((size_t)NTOT*Ii*2);
  __hip_bfloat16* routed  = (__hip_bfloat16*)alloc((size_t)Ntok*3*HIDD*2);
  __hip_bfloat16* ed_t    = (__hip_bfloat16*)alloc((size_t)9*HIDD*Ii*2);

  dim3 blk(256);

  // ================= attention =================
  prep_kernel<<<Ntok + 6144 + 128, blk, 0, stream>>>(x, norm1_w, bp, xn, xn_lo, betab,
                                                     wq, wk, wv, wo, fa, ga,
                                                     wqkv_t, wqkv_lo, wo_t, wo_lo,
                                                     fb, gb, fbgb_t);
  // QKV + fg-stage1 fused (N=3200; fg epilogue -> atmp12 via resid ptr)
  gemm3_k<3,128><<<dim3(25,16,1), blk, 0, stream>>>(xn, xn_lo, wqkv_t, wqkv_lo, qkvlin,
                                                    Ntok, NQKV, HIDD, (const float*)atmp12);
  conv_norm_kernel<<<dim3(Ntok,3,1), blk, 0, stream>>>(qkvlin, cq, ck, cv, qc, kc, vc);
  gemm_k<8,0,128><<<dim3(16,16,1), blk, 0, stream>>>(atmp12, fbgb_t, gbuf, Ntok, 2048, 128, 2*Dd,
                                                     A_log, nullptr, nullptr,
                                                     (const int*)gatebuf, nullptr, dt_bias);
  scan_kernel<<<Bb*Hh*16, dim3(64), 0, stream>>>(qc, kc, vc, gbuf, betab, obuf);
  onorm_gate_split_kernel<<<(Ntok*Hh)/4, blk, 0, stream>>>(obuf, onorm_w, gatebuf, obuf_hi, obuf_lo);
  gemm3_k<2,64><<<dim3(16,16,1), blk, 0, stream>>>(obuf_hi, obuf_lo, wo_t, wo_lo, hbuf,
                                                   Ntok, HIDD, Pp, x);

  // ================= MoE (shared expert folded in as expert 8) =================
  // fused: rms+router-logits (blocks 0..1023) + expert weight transpose (blocks 1024..)
  moe_prep_kernel<<<Ntok + 27*1024, blk, 0, stream>>>(hbuf, norm2_w, gate_w, hn, scores,
                                                      wg_e, wu_e, wg_s, wu_s, wd_e, wd_s,
                                                      egu_t, ed_t);
  router_compact_kernel<<<1, dim3(1024), 0, stream>>>(scores, gate_b, counts, prefix,
                                                      ctok, cslot, cwt);
  gemm_k<6,0,128><<<dim3(12,16,9), blk, 0, stream>>>(hn, egu_t, act, Ntok, 2*Ii, HIDD, HIDD,
                                                     nullptr, counts, prefix, ctok, nullptr, nullptr);
  gemm_k<4,0,128><<<dim3(8,16,9), blk, 0, stream>>>(act, ed_t, routed, Ntok, HIDD, Ii, Ii,
                                                    nullptr, counts, prefix, ctok, cslot, cwt);

  final_kernel<<<(Ntok*HIDD+255)/256, blk, 0, stream>>>(hbuf, routed, out);
}